// Round 1
// baseline (4606.371 us; speedup 1.0000x reference)
//
#include <hip/hip_runtime.h>
#include <math.h>

// Problem dims (fixed by reference)
#define D_MODEL 384
#define N_LAYER 8
#define N_MELS  80
#define D_STATE 16
#define D_CONV  4
#define D_INNER 768
#define DT_RANK 24
#define BB      4
#define LL      512
#define MTOK    (BB*LL)   // 2048

#define BMt 64
#define BNt 64
#define BKt 16

__device__ __forceinline__ float silu_f(float x) { return x / (1.f + __expf(-x)); }

// ---------------------------------------------------------------------------
// Generic tiled fp32 GEMM: C[M,N] = A[M,K] @ W[K,N]  (+ epilogue)
// EPI: 0 none, 1 +bias, 2 softplus(.+bias), 3 +resid (resid stride ldc, may alias C)
// ---------------------------------------------------------------------------
template<int EPI>
__global__ __launch_bounds__(256) void gemm_f32(
    const float* __restrict__ A, int lda,
    const float* __restrict__ W, int ldw,
    const float* __restrict__ bias,
    const float* __restrict__ resid,
    float* __restrict__ C, int ldc,
    int M, int N, int K)
{
  __shared__ float As[BKt][BMt];   // [k][m]
  __shared__ float Ws[BKt][BNt];   // [k][n]
  const int tid = threadIdx.x;
  const int tx = tid & 15, ty = tid >> 4;
  const int m0 = blockIdx.y * BMt, n0 = blockIdx.x * BNt;
  const int am = tid >> 2, ak4 = (tid & 3) << 2;   // A tile: 64 rows x 16 k
  const int wk = tid >> 4, wn4 = (tid & 15) << 2;  // W tile: 16 k x 64 n

  float acc[4][4] = {};

  for (int k0 = 0; k0 < K; k0 += BKt) {
    // --- load A tile (transposed into LDS) ---
    float4 va = make_float4(0.f, 0.f, 0.f, 0.f);
    {
      int m = m0 + am;
      if (m < M) {
        if (k0 + ak4 + 3 < K) {
          va = *reinterpret_cast<const float4*>(&A[(size_t)m * lda + k0 + ak4]);
        } else {
          float t[4];
          #pragma unroll
          for (int j = 0; j < 4; ++j)
            t[j] = (k0 + ak4 + j < K) ? A[(size_t)m * lda + k0 + ak4 + j] : 0.f;
          va = make_float4(t[0], t[1], t[2], t[3]);
        }
      }
    }
    As[ak4 + 0][am] = va.x;
    As[ak4 + 1][am] = va.y;
    As[ak4 + 2][am] = va.z;
    As[ak4 + 3][am] = va.w;

    // --- load W tile ---
    float4 vw = make_float4(0.f, 0.f, 0.f, 0.f);
    {
      int kw = k0 + wk;
      if (kw < K) {
        if (n0 + wn4 + 3 < N) {
          vw = *reinterpret_cast<const float4*>(&W[(size_t)kw * ldw + n0 + wn4]);
        } else {
          float t[4];
          #pragma unroll
          for (int j = 0; j < 4; ++j)
            t[j] = (n0 + wn4 + j < N) ? W[(size_t)kw * ldw + n0 + wn4 + j] : 0.f;
          vw = make_float4(t[0], t[1], t[2], t[3]);
        }
      }
    }
    *reinterpret_cast<float4*>(&Ws[wk][wn4]) = vw;

    __syncthreads();
    #pragma unroll
    for (int kk = 0; kk < BKt; ++kk) {
      const float4 a4 = *reinterpret_cast<const float4*>(&As[kk][ty << 2]);
      const float4 w4 = *reinterpret_cast<const float4*>(&Ws[kk][tx << 2]);
      float av[4] = {a4.x, a4.y, a4.z, a4.w};
      float wv[4] = {w4.x, w4.y, w4.z, w4.w};
      #pragma unroll
      for (int i = 0; i < 4; ++i)
        #pragma unroll
        for (int j = 0; j < 4; ++j)
          acc[i][j] += av[i] * wv[j];
    }
    __syncthreads();
  }

  #pragma unroll
  for (int i = 0; i < 4; ++i) {
    int row = m0 + (ty << 2) + i;
    if (row >= M) continue;
    #pragma unroll
    for (int j = 0; j < 4; ++j) {
      int col = n0 + (tx << 2) + j;
      if (col >= N) continue;
      float v = acc[i][j];
      if (EPI == 1) v += bias[col];
      if (EPI == 2) { v += bias[col]; v = (v > 20.f) ? v : log1pf(__expf(v)); }
      if (EPI == 3) v += resid[(size_t)row * ldc + col];
      C[(size_t)row * ldc + col] = v;
    }
  }
}

// ---------------------------------------------------------------------------
// RMSNorm: one wave (64 lanes) per row of N elements
// ---------------------------------------------------------------------------
__global__ __launch_bounds__(256) void rmsnorm_kernel(
    const float* __restrict__ x, const float* __restrict__ w,
    float* __restrict__ out, int M, int N)
{
  int gw = (blockIdx.x * blockDim.x + threadIdx.x) >> 6;
  int lane = threadIdx.x & 63;
  if (gw >= M) return;
  const float* row = x + (size_t)gw * N;
  float ss = 0.f;
  for (int j = lane; j < N; j += 64) { float v = row[j]; ss += v * v; }
  #pragma unroll
  for (int off = 32; off; off >>= 1) ss += __shfl_xor(ss, off, 64);
  float scale = rsqrtf(ss / (float)N + 1e-5f);
  float* orow = out + (size_t)gw * N;
  for (int j = lane; j < N; j += 64) orow[j] = row[j] * scale * w[j];
}

// ---------------------------------------------------------------------------
// Depthwise causal conv (k=4) + bias + SiLU.
// Input: xr columns [0,768) with row stride 1536. Output xs: M x 768.
// ---------------------------------------------------------------------------
__global__ __launch_bounds__(256) void conv_silu_kernel(
    const float* __restrict__ xr, const float* __restrict__ cw,
    const float* __restrict__ cb, float* __restrict__ xs)
{
  int idx = blockIdx.x * 256 + threadIdx.x;
  if (idx >= MTOK * D_INNER) return;
  int m = idx / D_INNER;
  int d = idx - m * D_INNER;
  int b = m >> 9, l = m & 511;
  float acc = 0.f;
  #pragma unroll
  for (int k = 0; k < D_CONV; ++k) {
    int t = l - (D_CONV - 1) + k;
    if (t >= 0) acc += xr[((size_t)(b * LL + t)) * (2 * D_INNER) + d] * cw[d * D_CONV + k];
  }
  acc += cb[d];
  xs[idx] = silu_f(acc);
}

// ---------------------------------------------------------------------------
// Selective scan. Thread = (b, d, n). 16 lanes (n) reduce via shfl_xor.
// Fuses: A = -exp(A_log), y = scan + u*D, gate y *= silu(res).
// ---------------------------------------------------------------------------
__global__ __launch_bounds__(256) void scan_kernel(
    const float* __restrict__ xs,     // M x 768 (u)
    const float* __restrict__ delta,  // M x 768
    const float* __restrict__ xdbl,   // M x 56 (dt|B|C)
    const float* __restrict__ A_log,  // 768 x 16 (layer slice)
    const float* __restrict__ Dp,     // 768
    const float* __restrict__ xr,     // M x 1536 (res = cols 768..)
    float* __restrict__ yg)           // M x 768
{
  int tid = blockIdx.x * 256 + threadIdx.x;
  int n = tid & 15;
  int c = tid >> 4;                 // 0..3071
  if (c >= BB * D_INNER) return;
  int b = c / D_INNER;
  int d = c - b * D_INNER;
  const float Aval = -__expf(A_log[d * D_STATE + n]);
  const float Dv = Dp[d];
  float h = 0.f;
  for (int l = 0; l < LL; ++l) {
    size_t m = (size_t)(b * LL + l);
    float dv = delta[m * D_INNER + d];
    float uv = xs[m * D_INNER + d];
    float Bv = xdbl[m * 56 + DT_RANK + n];
    float Cv = xdbl[m * 56 + DT_RANK + D_STATE + n];
    h = __expf(dv * Aval) * h + (dv * Bv) * uv;
    float contrib = h * Cv;
    contrib += __shfl_xor(contrib, 1, 64);
    contrib += __shfl_xor(contrib, 2, 64);
    contrib += __shfl_xor(contrib, 4, 64);
    contrib += __shfl_xor(contrib, 8, 64);
    if (n == 0) {
      float y = contrib + uv * Dv;
      float r = xr[m * (2 * D_INNER) + D_INNER + d];
      yg[m * D_INNER + d] = y * silu_f(r);
    }
  }
}

// ---------------------------------------------------------------------------
// Attention: out[b,q,:] = softmax_k(h[b,q,:]·enc[b,k,:]) @ enc[b]
// One block handles TQ q-rows. 512 threads.
// ---------------------------------------------------------------------------
#define TQ 8
__global__ __launch_bounds__(512) void attn_kernel(
    const float* __restrict__ h, const float* __restrict__ enc,
    float* __restrict__ out)
{
  __shared__ float hrow[TQ][D_MODEL];
  __shared__ float p[TQ][LL];
  int blk = blockIdx.x;
  int b = blk / (LL / TQ);
  int q0 = (blk % (LL / TQ)) * TQ;
  int tid = threadIdx.x;

  for (int i = tid; i < TQ * D_MODEL; i += 512) {
    int qi = i / D_MODEL, j = i - qi * D_MODEL;
    hrow[qi][j] = h[((size_t)b * LL + q0 + qi) * D_MODEL + j];
  }
  __syncthreads();

  // scores: thread tid handles k = tid
  {
    int k = tid;
    const float* er = enc + ((size_t)b * LL + k) * D_MODEL;
    float acc[TQ] = {};
    for (int j = 0; j < D_MODEL; ++j) {
      float e = er[j];
      #pragma unroll
      for (int qi = 0; qi < TQ; ++qi) acc[qi] += hrow[qi][j] * e;
    }
    #pragma unroll
    for (int qi = 0; qi < TQ; ++qi) p[qi][k] = acc[qi];
  }
  __syncthreads();

  // softmax: wave w handles row w
  {
    int w = tid >> 6, lane = tid & 63;
    float mx = -1e30f;
    for (int k = lane; k < LL; k += 64) mx = fmaxf(mx, p[w][k]);
    #pragma unroll
    for (int off = 32; off; off >>= 1) mx = fmaxf(mx, __shfl_xor(mx, off, 64));
    float sum = 0.f;
    for (int k = lane; k < LL; k += 64) { float e = __expf(p[w][k] - mx); p[w][k] = e; sum += e; }
    #pragma unroll
    for (int off = 32; off; off >>= 1) sum += __shfl_xor(sum, off, 64);
    float inv = 1.f / sum;
    for (int k = lane; k < LL; k += 64) p[w][k] *= inv;
  }
  __syncthreads();

  // AV: threads 0..383 each own one d
  if (tid < D_MODEL) {
    int d = tid;
    float acc[TQ] = {};
    for (int k = 0; k < LL; ++k) {
      float e = enc[((size_t)b * LL + k) * D_MODEL + d];
      #pragma unroll
      for (int qi = 0; qi < TQ; ++qi) acc[qi] += p[qi][k] * e;
    }
    #pragma unroll
    for (int qi = 0; qi < TQ; ++qi)
      out[((size_t)b * LL + q0 + qi) * D_MODEL + d] = acc[qi];
  }
}

// ---------------------------------------------------------------------------
extern "C" void kernel_launch(void* const* d_in, const int* in_sizes, int n_in,
                              void* d_out, int out_size, void* d_ws, size_t ws_size,
                              hipStream_t stream) {
  const float* x        = (const float*)d_in[0];
  const float* enc      = (const float*)d_in[1];
  const float* w_in     = (const float*)d_in[2];
  const float* b_in     = (const float*)d_in[3];
  const float* ln_w     = (const float*)d_in[4];
  const float* inproj_w = (const float*)d_in[5];
  const float* conv_w   = (const float*)d_in[6];
  const float* conv_b   = (const float*)d_in[7];
  const float* xproj_w  = (const float*)d_in[8];
  const float* dtproj_w = (const float*)d_in[9];
  const float* dtproj_b = (const float*)d_in[10];
  const float* A_log    = (const float*)d_in[11];
  const float* Dvec     = (const float*)d_in[12];
  const float* outproj_w= (const float*)d_in[13];
  const float* normf_w  = (const float*)d_in[14];
  const float* w_out    = (const float*)d_in[15];

  float* ws = (float*)d_ws;
  float* h    = ws; ws += MTOK * D_MODEL;
  float* hn   = ws; ws += MTOK * D_MODEL;
  float* xr   = ws; ws += MTOK * 2 * D_INNER;
  float* xs   = ws; ws += MTOK * D_INNER;
  float* xdbl = ws; ws += MTOK * 56;
  float* delta= ws; ws += MTOK * D_INNER;
  float* yg   = ws; ws += MTOK * D_INNER;
  float* h2   = ws; ws += MTOK * D_MODEL;

  dim3 blk256(256), blk512(512);

  // input projection: h = x @ w_in + b_in
  gemm_f32<1><<<dim3(D_MODEL / BNt, MTOK / BMt), blk256, 0, stream>>>(
      x, N_MELS, w_in, D_MODEL, b_in, nullptr, h, D_MODEL, MTOK, D_MODEL, N_MELS);

  auto mamba = [&](float* hcur, int i) {
    rmsnorm_kernel<<<MTOK * 64 / 256, blk256, 0, stream>>>(hcur, ln_w + (size_t)i * D_MODEL, hn, MTOK, D_MODEL);
    gemm_f32<0><<<dim3(2 * D_INNER / BNt, MTOK / BMt), blk256, 0, stream>>>(
        hn, D_MODEL, inproj_w + (size_t)i * D_MODEL * 2 * D_INNER, 2 * D_INNER,
        nullptr, nullptr, xr, 2 * D_INNER, MTOK, 2 * D_INNER, D_MODEL);
    conv_silu_kernel<<<MTOK * D_INNER / 256, blk256, 0, stream>>>(
        xr, conv_w + (size_t)i * D_INNER * D_CONV, conv_b + (size_t)i * D_INNER, xs);
    gemm_f32<0><<<dim3(1, MTOK / BMt), blk256, 0, stream>>>(
        xs, D_INNER, xproj_w + (size_t)i * D_INNER * 56, 56,
        nullptr, nullptr, xdbl, 56, MTOK, 56, D_INNER);
    gemm_f32<2><<<dim3(D_INNER / BNt, MTOK / BMt), blk256, 0, stream>>>(
        xdbl, 56, dtproj_w + (size_t)i * DT_RANK * D_INNER, D_INNER,
        dtproj_b + (size_t)i * D_INNER, nullptr, delta, D_INNER, MTOK, D_INNER, DT_RANK);
    scan_kernel<<<BB * D_INNER * D_STATE / 256, blk256, 0, stream>>>(
        xs, delta, xdbl, A_log + (size_t)i * D_INNER * D_STATE, Dvec + (size_t)i * D_INNER, xr, yg);
    gemm_f32<3><<<dim3(D_MODEL / BNt, MTOK / BMt), blk256, 0, stream>>>(
        yg, D_INNER, outproj_w + (size_t)i * D_INNER * D_MODEL, D_MODEL,
        nullptr, hcur, hcur, D_MODEL, MTOK, D_MODEL, D_INNER);
  };

  for (int i = 0; i < N_LAYER / 2; ++i) mamba(h, i);

  attn_kernel<<<MTOK / TQ, blk512, 0, stream>>>(h, enc, h2);

  for (int i = N_LAYER / 2; i < N_LAYER; ++i) mamba(h2, i);

  rmsnorm_kernel<<<MTOK * 64 / 256, blk256, 0, stream>>>(h2, normf_w, hn, MTOK, D_MODEL);
  gemm_f32<0><<<dim3((N_MELS + BNt - 1) / BNt, MTOK / BMt), blk256, 0, stream>>>(
      hn, D_MODEL, w_out, N_MELS, nullptr, nullptr, (float*)d_out, N_MELS, MTOK, N_MELS, D_MODEL);
}

// Round 4
// 2135.578 us; speedup vs baseline: 2.1570x; 2.1570x over previous
//
#include <hip/hip_runtime.h>
#include <math.h>

// Problem dims (fixed by reference)
#define D_MODEL 384
#define N_LAYER 8
#define N_MELS  80
#define D_STATE 16
#define D_CONV  4
#define D_INNER 768
#define DT_RANK 24
#define BB      4
#define LL      512
#define MTOK    (BB*LL)   // 2048

#define BMt 64
#define BNt 64
#define BKt 16

__device__ __forceinline__ float silu_f(float x) { return x / (1.f + __expf(-x)); }

// ---------------------------------------------------------------------------
// Generic tiled fp32 GEMM: C[M,N] = A[M,K] @ W[K,N]  (+ epilogue)
// EPI: 0 none, 1 +bias, 2 softplus(.+bias), 3 +resid (resid stride ldc, may alias C)
// ---------------------------------------------------------------------------
template<int EPI>
__global__ __launch_bounds__(256) void gemm_f32(
    const float* __restrict__ A, int lda,
    const float* __restrict__ W, int ldw,
    const float* __restrict__ bias,
    const float* __restrict__ resid,
    float* __restrict__ C, int ldc,
    int M, int N, int K)
{
  __shared__ float As[BKt][BMt];   // [k][m]
  __shared__ float Ws[BKt][BNt];   // [k][n]
  const int tid = threadIdx.x;
  const int tx = tid & 15, ty = tid >> 4;
  const int m0 = blockIdx.y * BMt, n0 = blockIdx.x * BNt;
  const int am = tid >> 2, ak4 = (tid & 3) << 2;   // A tile: 64 rows x 16 k
  const int wk = tid >> 4, wn4 = (tid & 15) << 2;  // W tile: 16 k x 64 n

  float acc[4][4] = {};

  for (int k0 = 0; k0 < K; k0 += BKt) {
    // --- load A tile (transposed into LDS) ---
    float4 va = make_float4(0.f, 0.f, 0.f, 0.f);
    {
      int m = m0 + am;
      if (m < M) {
        if (k0 + ak4 + 3 < K) {
          va = *reinterpret_cast<const float4*>(&A[(size_t)m * lda + k0 + ak4]);
        } else {
          float t[4];
          #pragma unroll
          for (int j = 0; j < 4; ++j)
            t[j] = (k0 + ak4 + j < K) ? A[(size_t)m * lda + k0 + ak4 + j] : 0.f;
          va = make_float4(t[0], t[1], t[2], t[3]);
        }
      }
    }
    As[ak4 + 0][am] = va.x;
    As[ak4 + 1][am] = va.y;
    As[ak4 + 2][am] = va.z;
    As[ak4 + 3][am] = va.w;

    // --- load W tile ---
    float4 vw = make_float4(0.f, 0.f, 0.f, 0.f);
    {
      int kw = k0 + wk;
      if (kw < K) {
        if (n0 + wn4 + 3 < N) {
          vw = *reinterpret_cast<const float4*>(&W[(size_t)kw * ldw + n0 + wn4]);
        } else {
          float t[4];
          #pragma unroll
          for (int j = 0; j < 4; ++j)
            t[j] = (n0 + wn4 + j < N) ? W[(size_t)kw * ldw + n0 + wn4 + j] : 0.f;
          vw = make_float4(t[0], t[1], t[2], t[3]);
        }
      }
    }
    *reinterpret_cast<float4*>(&Ws[wk][wn4]) = vw;

    __syncthreads();
    #pragma unroll
    for (int kk = 0; kk < BKt; ++kk) {
      const float4 a4 = *reinterpret_cast<const float4*>(&As[kk][ty << 2]);
      const float4 w4 = *reinterpret_cast<const float4*>(&Ws[kk][tx << 2]);
      float av[4] = {a4.x, a4.y, a4.z, a4.w};
      float wv[4] = {w4.x, w4.y, w4.z, w4.w};
      #pragma unroll
      for (int i = 0; i < 4; ++i)
        #pragma unroll
        for (int j = 0; j < 4; ++j)
          acc[i][j] += av[i] * wv[j];
    }
    __syncthreads();
  }

  #pragma unroll
  for (int i = 0; i < 4; ++i) {
    int row = m0 + (ty << 2) + i;
    if (row >= M) continue;
    #pragma unroll
    for (int j = 0; j < 4; ++j) {
      int col = n0 + (tx << 2) + j;
      if (col >= N) continue;
      float v = acc[i][j];
      if (EPI == 1) v += bias[col];
      if (EPI == 2) { v += bias[col]; v = (v > 20.f) ? v : log1pf(__expf(v)); }
      if (EPI == 3) v += resid[(size_t)row * ldc + col];
      C[(size_t)row * ldc + col] = v;
    }
  }
}

// ---------------------------------------------------------------------------
// RMSNorm: one wave (64 lanes) per row of N elements
// ---------------------------------------------------------------------------
__global__ __launch_bounds__(256) void rmsnorm_kernel(
    const float* __restrict__ x, const float* __restrict__ w,
    float* __restrict__ out, int M, int N)
{
  int gw = (blockIdx.x * blockDim.x + threadIdx.x) >> 6;
  int lane = threadIdx.x & 63;
  if (gw >= M) return;
  const float* row = x + (size_t)gw * N;
  float ss = 0.f;
  for (int j = lane; j < N; j += 64) { float v = row[j]; ss += v * v; }
  #pragma unroll
  for (int off = 32; off; off >>= 1) ss += __shfl_xor(ss, off, 64);
  float scale = rsqrtf(ss / (float)N + 1e-5f);
  float* orow = out + (size_t)gw * N;
  for (int j = lane; j < N; j += 64) orow[j] = row[j] * scale * w[j];
}

// ---------------------------------------------------------------------------
// Depthwise causal conv (k=4) + bias + SiLU.
// ---------------------------------------------------------------------------
__global__ __launch_bounds__(256) void conv_silu_kernel(
    const float* __restrict__ xr, const float* __restrict__ cw,
    const float* __restrict__ cb, float* __restrict__ xs)
{
  int idx = blockIdx.x * 256 + threadIdx.x;
  if (idx >= MTOK * D_INNER) return;
  int m = idx / D_INNER;
  int d = idx - m * D_INNER;
  int b = m >> 9, l = m & 511;
  float acc = 0.f;
  #pragma unroll
  for (int k = 0; k < D_CONV; ++k) {
    int t = l - (D_CONV - 1) + k;
    if (t >= 0) acc += xr[((size_t)(b * LL + t)) * (2 * D_INNER) + d] * cw[d * D_CONV + k];
  }
  acc += cb[d];
  xs[idx] = silu_f(acc);
}

// ---------------------------------------------------------------------------
// Chunked parallel selective scan.
// Block = (d, b): 256 threads = 16 chunks (c) x 16 states (n), tid = c*16+n.
// Each chunk covers T=32 timesteps; the affine recurrence h <- a*h + dBu
// is composed per-chunk (P, S), chunk entry states built serially (16 steps),
// then each chunk replays its 32 steps from the correct h0 and emits y with
// the D-term + silu(res) gate fused.
// ---------------------------------------------------------------------------
#define SCAN_T  32
#define SCAN_NC 16
__global__ __launch_bounds__(256) void scan_kernel2(
    const float* __restrict__ xs,     // M x 768 (u)
    const float* __restrict__ delta,  // M x 768
    const float* __restrict__ xdbl,   // M x 56 (dt|B|C)
    const float* __restrict__ A_log,  // 768 x 16 (layer slice)
    const float* __restrict__ Dp,     // 768
    const float* __restrict__ xr,     // M x 1536 (res = cols 768..)
    float* __restrict__ yg)           // M x 768
{
  __shared__ float sdelta[LL];
  __shared__ float su[LL];
  __shared__ float sP[SCAN_NC][D_STATE];
  __shared__ float sS[SCAN_NC][D_STATE];
  __shared__ float sH0[SCAN_NC][D_STATE];

  const int d = blockIdx.x;
  const int b = blockIdx.y;
  const int tid = threadIdx.x;
  const int n = tid & 15;
  const int c = tid >> 4;

  // stage the delta / u columns for this (b,d) into LDS
  for (int l = tid; l < LL; l += 256) {
    size_t m = (size_t)(b * LL + l);
    sdelta[l] = delta[m * D_INNER + d];
    su[l]     = xs[m * D_INNER + d];
  }

  const float Aval = -__expf(A_log[d * D_STATE + n]);
  __syncthreads();

  // Phase 1: per-chunk affine composition (P, S)
  {
    float P = 1.f, S = 0.f;
    const int l0 = c * SCAN_T;
    #pragma unroll 4
    for (int t = 0; t < SCAN_T; ++t) {
      int l = l0 + t;
      size_t m = (size_t)(b * LL + l);
      float dv = sdelta[l];
      float uv = su[l];
      float Bv = xdbl[m * 56 + DT_RANK + n];
      float a = __expf(dv * Aval);
      P *= a;
      S = a * S + (dv * Bv) * uv;
    }
    sP[c][n] = P;
    sS[c][n] = S;
  }
  __syncthreads();

  // Phase 2: serial compose across chunks (16 threads, one per state n)
  if (tid < D_STATE) {
    float h = 0.f;
    #pragma unroll
    for (int cc = 0; cc < SCAN_NC; ++cc) {
      sH0[cc][tid] = h;
      h = sP[cc][tid] * h + sS[cc][tid];
    }
  }
  __syncthreads();

  // Phase 3: replay chunk from correct entry state, emit gated output
  {
    const float Dv = Dp[d];
    float h = sH0[c][n];
    const int l0 = c * SCAN_T;
    #pragma unroll 4
    for (int t = 0; t < SCAN_T; ++t) {
      int l = l0 + t;
      size_t m = (size_t)(b * LL + l);
      float dv = sdelta[l];
      float uv = su[l];
      float Bv = xdbl[m * 56 + DT_RANK + n];
      float Cv = xdbl[m * 56 + DT_RANK + D_STATE + n];
      float a = __expf(dv * Aval);
      h = a * h + (dv * Bv) * uv;
      float contrib = h * Cv;
      contrib += __shfl_xor(contrib, 1, 64);
      contrib += __shfl_xor(contrib, 2, 64);
      contrib += __shfl_xor(contrib, 4, 64);
      contrib += __shfl_xor(contrib, 8, 64);
      if (n == 0) {
        float y = contrib + uv * Dv;
        float r = xr[m * (2 * D_INNER) + D_INNER + d];
        yg[m * D_INNER + d] = y * silu_f(r);
      }
    }
  }
}

// ---------------------------------------------------------------------------
// Attention: out[b,q,:] = softmax_k(h[b,q,:]·enc[b,k,:]) @ enc[b]
// ---------------------------------------------------------------------------
#define TQ 8
__global__ __launch_bounds__(512) void attn_kernel(
    const float* __restrict__ h, const float* __restrict__ enc,
    float* __restrict__ out)
{
  __shared__ float hrow[TQ][D_MODEL];
  __shared__ float p[TQ][LL];
  int blk = blockIdx.x;
  int b = blk / (LL / TQ);
  int q0 = (blk % (LL / TQ)) * TQ;
  int tid = threadIdx.x;

  for (int i = tid; i < TQ * D_MODEL; i += 512) {
    int qi = i / D_MODEL, j = i - qi * D_MODEL;
    hrow[qi][j] = h[((size_t)b * LL + q0 + qi) * D_MODEL + j];
  }
  __syncthreads();

  {
    int k = tid;
    const float* er = enc + ((size_t)b * LL + k) * D_MODEL;
    float acc[TQ] = {};
    for (int j = 0; j < D_MODEL; ++j) {
      float e = er[j];
      #pragma unroll
      for (int qi = 0; qi < TQ; ++qi) acc[qi] += hrow[qi][j] * e;
    }
    #pragma unroll
    for (int qi = 0; qi < TQ; ++qi) p[qi][k] = acc[qi];
  }
  __syncthreads();

  {
    int w = tid >> 6, lane = tid & 63;
    float mx = -1e30f;
    for (int k = lane; k < LL; k += 64) mx = fmaxf(mx, p[w][k]);
    #pragma unroll
    for (int off = 32; off; off >>= 1) mx = fmaxf(mx, __shfl_xor(mx, off, 64));
    float sum = 0.f;
    for (int k = lane; k < LL; k += 64) { float e = __expf(p[w][k] - mx); p[w][k] = e; sum += e; }
    #pragma unroll
    for (int off = 32; off; off >>= 1) sum += __shfl_xor(sum, off, 64);
    float inv = 1.f / sum;
    for (int k = lane; k < LL; k += 64) p[w][k] *= inv;
  }
  __syncthreads();

  if (tid < D_MODEL) {
    int d = tid;
    float acc[TQ] = {};
    for (int k = 0; k < LL; ++k) {
      float e = enc[((size_t)b * LL + k) * D_MODEL + d];
      #pragma unroll
      for (int qi = 0; qi < TQ; ++qi) acc[qi] += p[qi][k] * e;
    }
    #pragma unroll
    for (int qi = 0; qi < TQ; ++qi)
      out[((size_t)b * LL + q0 + qi) * D_MODEL + d] = acc[qi];
  }
}

// ---------------------------------------------------------------------------
extern "C" void kernel_launch(void* const* d_in, const int* in_sizes, int n_in,
                              void* d_out, int out_size, void* d_ws, size_t ws_size,
                              hipStream_t stream) {
  const float* x        = (const float*)d_in[0];
  const float* enc      = (const float*)d_in[1];
  const float* w_in     = (const float*)d_in[2];
  const float* b_in     = (const float*)d_in[3];
  const float* ln_w     = (const float*)d_in[4];
  const float* inproj_w = (const float*)d_in[5];
  const float* conv_w   = (const float*)d_in[6];
  const float* conv_b   = (const float*)d_in[7];
  const float* xproj_w  = (const float*)d_in[8];
  const float* dtproj_w = (const float*)d_in[9];
  const float* dtproj_b = (const float*)d_in[10];
  const float* A_log    = (const float*)d_in[11];
  const float* Dvec     = (const float*)d_in[12];
  const float* outproj_w= (const float*)d_in[13];
  const float* normf_w  = (const float*)d_in[14];
  const float* w_out    = (const float*)d_in[15];

  float* ws = (float*)d_ws;
  float* h    = ws; ws += MTOK * D_MODEL;
  float* hn   = ws; ws += MTOK * D_MODEL;
  float* xr   = ws; ws += MTOK * 2 * D_INNER;
  float* xs   = ws; ws += MTOK * D_INNER;
  float* xdbl = ws; ws += MTOK * 56;
  float* delta= ws; ws += MTOK * D_INNER;
  float* yg   = ws; ws += MTOK * D_INNER;
  float* h2   = ws; ws += MTOK * D_MODEL;

  dim3 blk256(256), blk512(512);

  gemm_f32<1><<<dim3(D_MODEL / BNt, MTOK / BMt), blk256, 0, stream>>>(
      x, N_MELS, w_in, D_MODEL, b_in, nullptr, h, D_MODEL, MTOK, D_MODEL, N_MELS);

  auto mamba = [&](float* hcur, int i) {
    rmsnorm_kernel<<<MTOK * 64 / 256, blk256, 0, stream>>>(hcur, ln_w + (size_t)i * D_MODEL, hn, MTOK, D_MODEL);
    gemm_f32<0><<<dim3(2 * D_INNER / BNt, MTOK / BMt), blk256, 0, stream>>>(
        hn, D_MODEL, inproj_w + (size_t)i * D_MODEL * 2 * D_INNER, 2 * D_INNER,
        nullptr, nullptr, xr, 2 * D_INNER, MTOK, 2 * D_INNER, D_MODEL);
    conv_silu_kernel<<<MTOK * D_INNER / 256, blk256, 0, stream>>>(
        xr, conv_w + (size_t)i * D_INNER * D_CONV, conv_b + (size_t)i * D_INNER, xs);
    gemm_f32<0><<<dim3(1, MTOK / BMt), blk256, 0, stream>>>(
        xs, D_INNER, xproj_w + (size_t)i * D_INNER * 56, 56,
        nullptr, nullptr, xdbl, 56, MTOK, 56, D_INNER);
    gemm_f32<2><<<dim3(D_INNER / BNt, MTOK / BMt), blk256, 0, stream>>>(
        xdbl, 56, dtproj_w + (size_t)i * DT_RANK * D_INNER, D_INNER,
        dtproj_b + (size_t)i * D_INNER, nullptr, delta, D_INNER, MTOK, D_INNER, DT_RANK);
    scan_kernel2<<<dim3(D_INNER, BB), blk256, 0, stream>>>(
        xs, delta, xdbl, A_log + (size_t)i * D_INNER * D_STATE, Dvec + (size_t)i * D_INNER, xr, yg);
    gemm_f32<3><<<dim3(D_MODEL / BNt, MTOK / BMt), blk256, 0, stream>>>(
        yg, D_INNER, outproj_w + (size_t)i * D_INNER * D_MODEL, D_MODEL,
        nullptr, hcur, hcur, D_MODEL, MTOK, D_MODEL, D_INNER);
  };

  for (int i = 0; i < N_LAYER / 2; ++i) mamba(h, i);

  attn_kernel<<<MTOK / TQ, blk512, 0, stream>>>(h, enc, h2);

  for (int i = N_LAYER / 2; i < N_LAYER; ++i) mamba(h2, i);

  rmsnorm_kernel<<<MTOK * 64 / 256, blk256, 0, stream>>>(h2, normf_w, hn, MTOK, D_MODEL);
  gemm_f32<0><<<dim3((N_MELS + BNt - 1) / BNt, MTOK / BMt), blk256, 0, stream>>>(
      hn, D_MODEL, w_out, N_MELS, nullptr, nullptr, (float*)d_out, N_MELS, MTOK, N_MELS, D_MODEL);
}

// Round 5
// 1462.266 us; speedup vs baseline: 3.1502x; 1.4605x over previous
//
#include <hip/hip_runtime.h>
#include <hip/hip_bf16.h>
#include <math.h>

// Problem dims (fixed by reference)
#define D_MODEL 384
#define N_LAYER 8
#define N_MELS  80
#define D_STATE 16
#define D_CONV  4
#define D_INNER 768
#define DT_RANK 24
#define BB      4
#define LL      512
#define MTOK    (BB*LL)   // 2048

#define BMt 64
#define BNt 64
#define BKt 16

typedef __attribute__((ext_vector_type(8))) short bf16x8;
typedef __attribute__((ext_vector_type(4))) float f32x4;

__device__ __forceinline__ float silu_f(float x) { return x / (1.f + __expf(-x)); }

// ---------------------------------------------------------------------------
// Generic tiled fp32 GEMM (small/sensitive ops): C[M,N] = A[M,K] @ W[K,N]
// EPI: 0 none, 1 +bias, 2 softplus(.+bias), 3 +resid
// ---------------------------------------------------------------------------
template<int EPI>
__global__ __launch_bounds__(256) void gemm_f32(
    const float* __restrict__ A, int lda,
    const float* __restrict__ W, int ldw,
    const float* __restrict__ bias,
    const float* __restrict__ resid,
    float* __restrict__ C, int ldc,
    int M, int N, int K)
{
  __shared__ float As[BKt][BMt];   // [k][m]
  __shared__ float Ws[BKt][BNt];   // [k][n]
  const int tid = threadIdx.x;
  const int tx = tid & 15, ty = tid >> 4;
  const int m0 = blockIdx.y * BMt, n0 = blockIdx.x * BNt;
  const int am = tid >> 2, ak4 = (tid & 3) << 2;
  const int wk = tid >> 4, wn4 = (tid & 15) << 2;

  float acc[4][4] = {};

  for (int k0 = 0; k0 < K; k0 += BKt) {
    float4 va = make_float4(0.f, 0.f, 0.f, 0.f);
    {
      int m = m0 + am;
      if (m < M) {
        if (k0 + ak4 + 3 < K) {
          va = *reinterpret_cast<const float4*>(&A[(size_t)m * lda + k0 + ak4]);
        } else {
          float t[4];
          #pragma unroll
          for (int j = 0; j < 4; ++j)
            t[j] = (k0 + ak4 + j < K) ? A[(size_t)m * lda + k0 + ak4 + j] : 0.f;
          va = make_float4(t[0], t[1], t[2], t[3]);
        }
      }
    }
    As[ak4 + 0][am] = va.x;
    As[ak4 + 1][am] = va.y;
    As[ak4 + 2][am] = va.z;
    As[ak4 + 3][am] = va.w;

    float4 vw = make_float4(0.f, 0.f, 0.f, 0.f);
    {
      int kw = k0 + wk;
      if (kw < K) {
        if (n0 + wn4 + 3 < N) {
          vw = *reinterpret_cast<const float4*>(&W[(size_t)kw * ldw + n0 + wn4]);
        } else {
          float t[4];
          #pragma unroll
          for (int j = 0; j < 4; ++j)
            t[j] = (n0 + wn4 + j < N) ? W[(size_t)kw * ldw + n0 + wn4 + j] : 0.f;
          vw = make_float4(t[0], t[1], t[2], t[3]);
        }
      }
    }
    *reinterpret_cast<float4*>(&Ws[wk][wn4]) = vw;

    __syncthreads();
    #pragma unroll
    for (int kk = 0; kk < BKt; ++kk) {
      const float4 a4 = *reinterpret_cast<const float4*>(&As[kk][ty << 2]);
      const float4 w4 = *reinterpret_cast<const float4*>(&Ws[kk][tx << 2]);
      float av[4] = {a4.x, a4.y, a4.z, a4.w};
      float wv[4] = {w4.x, w4.y, w4.z, w4.w};
      #pragma unroll
      for (int i = 0; i < 4; ++i)
        #pragma unroll
        for (int j = 0; j < 4; ++j)
          acc[i][j] += av[i] * wv[j];
    }
    __syncthreads();
  }

  #pragma unroll
  for (int i = 0; i < 4; ++i) {
    int row = m0 + (ty << 2) + i;
    if (row >= M) continue;
    #pragma unroll
    for (int j = 0; j < 4; ++j) {
      int col = n0 + (tx << 2) + j;
      if (col >= N) continue;
      float v = acc[i][j];
      if (EPI == 1) v += bias[col];
      if (EPI == 2) { v += bias[col]; v = (v > 20.f) ? v : log1pf(__expf(v)); }
      if (EPI == 3) v += resid[(size_t)row * ldc + col];
      C[(size_t)row * ldc + col] = v;
    }
  }
}

// ---------------------------------------------------------------------------
// bf16 MFMA GEMM: C_f32[M,N] = A_bf16[M,K] @ WT_bf16[N,K]   (WT pre-transposed)
// 64x64 tile, BK=64, 4 waves; wave w computes rows [w*16, w*16+16) x 64 cols.
// mfma_f32_16x16x32_bf16: A lane l: m=l&15, k=(l>>4)*8+j ; B lane l: n=l&15,
// same k ; D lane l reg r: row=(l>>4)*4+r, col=l&15  [guide §3, m89-verified].
// EPI: 0 none, 3 +resid (resid stride ldc, may alias C).
// Requires M,N,K multiples of 64.
// ---------------------------------------------------------------------------
template<int EPI>
__global__ __launch_bounds__(256) void gemm_bf16(
    const __hip_bfloat16* __restrict__ A,   // [M][K]
    const __hip_bfloat16* __restrict__ WT,  // [N][K]
    const float* __restrict__ resid,
    float* __restrict__ C, int ldc,
    int M, int N, int K)
{
  __shared__ __align__(16) __hip_bfloat16 Asl[64][72];  // +8 pad: kill 64B-stride conflicts
  __shared__ __align__(16) __hip_bfloat16 Bsl[64][72];
  const int tid = threadIdx.x;
  const int wave = tid >> 6, lane = tid & 63;
  const int m0 = blockIdx.y * 64, n0 = blockIdx.x * 64;
  const int lrow = tid >> 2;          // staging: row 0..63
  const int lk   = (tid & 3) << 4;    // staging: k-offset {0,16,32,48}
  const int g16 = lane >> 4;          // 0..3
  const int l16 = lane & 15;

  f32x4 acc[4] = {};

  for (int k0 = 0; k0 < K; k0 += 64) {
    const uint4* ga = reinterpret_cast<const uint4*>(&A[(size_t)(m0 + lrow) * K + k0 + lk]);
    uint4* la = reinterpret_cast<uint4*>(&Asl[lrow][lk]);
    la[0] = ga[0]; la[1] = ga[1];
    const uint4* gb = reinterpret_cast<const uint4*>(&WT[(size_t)(n0 + lrow) * K + k0 + lk]);
    uint4* lb = reinterpret_cast<uint4*>(&Bsl[lrow][lk]);
    lb[0] = gb[0]; lb[1] = gb[1];
    __syncthreads();
    #pragma unroll
    for (int kk = 0; kk < 64; kk += 32) {
      bf16x8 a = *reinterpret_cast<const bf16x8*>(&Asl[wave * 16 + l16][kk + g16 * 8]);
      #pragma unroll
      for (int f = 0; f < 4; ++f) {
        bf16x8 b = *reinterpret_cast<const bf16x8*>(&Bsl[f * 16 + l16][kk + g16 * 8]);
        acc[f] = __builtin_amdgcn_mfma_f32_16x16x32_bf16(a, b, acc[f], 0, 0, 0);
      }
    }
    __syncthreads();
  }

  #pragma unroll
  for (int f = 0; f < 4; ++f) {
    #pragma unroll
    for (int r = 0; r < 4; ++r) {
      int row = m0 + wave * 16 + g16 * 4 + r;
      int col = n0 + f * 16 + l16;
      float v = acc[f][r];
      if (EPI == 3) v += resid[(size_t)row * ldc + col];
      C[(size_t)row * ldc + col] = v;
    }
  }
}

// ---------------------------------------------------------------------------
// Weight convert + transpose: src f32 [L][K][N] -> dst bf16 [L][N][K]
// ---------------------------------------------------------------------------
__global__ __launch_bounds__(256) void wconv_t_kernel(
    const float* __restrict__ src, __hip_bfloat16* __restrict__ dst,
    int K, int N)
{
  __shared__ float tile[32][33];
  int l = blockIdx.z;
  int kb = blockIdx.y * 32, nb = blockIdx.x * 32;
  int tn = threadIdx.x & 31, tk = threadIdx.x >> 5;  // 32 x 8
  const float* s = src + (size_t)l * K * N;
  __hip_bfloat16* dd = dst + (size_t)l * N * K;
  #pragma unroll
  for (int i = 0; i < 4; ++i) {
    int k = kb + tk + i * 8, n = nb + tn;
    tile[tk + i * 8][tn] = (k < K && n < N) ? s[(size_t)k * N + n] : 0.f;
  }
  __syncthreads();
  #pragma unroll
  for (int i = 0; i < 4; ++i) {
    int n = nb + tk + i * 8, k = kb + tn;
    if (n < N && k < K) dd[(size_t)n * K + k] = __float2bfloat16(tile[tn][tk + i * 8]);
  }
}

// ---------------------------------------------------------------------------
// RMSNorm: one wave per row; writes fp32 and bf16 copies
// ---------------------------------------------------------------------------
__global__ __launch_bounds__(256) void rmsnorm_kernel(
    const float* __restrict__ x, const float* __restrict__ w,
    float* __restrict__ out, __hip_bfloat16* __restrict__ outb, int M, int N)
{
  int gw = (blockIdx.x * blockDim.x + threadIdx.x) >> 6;
  int lane = threadIdx.x & 63;
  if (gw >= M) return;
  const float* row = x + (size_t)gw * N;
  float ss = 0.f;
  for (int j = lane; j < N; j += 64) { float v = row[j]; ss += v * v; }
  #pragma unroll
  for (int off = 32; off; off >>= 1) ss += __shfl_xor(ss, off, 64);
  float scale = rsqrtf(ss / (float)N + 1e-5f);
  float* orow = out + (size_t)gw * N;
  __hip_bfloat16* brow = outb + (size_t)gw * N;
  for (int j = lane; j < N; j += 64) {
    float v = row[j] * scale * w[j];
    orow[j] = v;
    brow[j] = __float2bfloat16(v);
  }
}

// ---------------------------------------------------------------------------
// Depthwise causal conv (k=4) + bias + SiLU.
// ---------------------------------------------------------------------------
__global__ __launch_bounds__(256) void conv_silu_kernel(
    const float* __restrict__ xr, const float* __restrict__ cw,
    const float* __restrict__ cb, float* __restrict__ xs)
{
  int idx = blockIdx.x * 256 + threadIdx.x;
  if (idx >= MTOK * D_INNER) return;
  int m = idx / D_INNER;
  int d = idx - m * D_INNER;
  int b = m >> 9, l = m & 511;
  float acc = 0.f;
  #pragma unroll
  for (int k = 0; k < D_CONV; ++k) {
    int t = l - (D_CONV - 1) + k;
    if (t >= 0) acc += xr[((size_t)(b * LL + t)) * (2 * D_INNER) + d] * cw[d * D_CONV + k];
  }
  acc += cb[d];
  xs[idx] = silu_f(acc);
}

// ---------------------------------------------------------------------------
// Chunked parallel selective scan, XCD-swizzled block mapping.
// Linear grid of 3072 blocks; decode keeps all 32 blocks that share a 128B
// cache line of delta/xs/xr/yg (d-group of 32, same b) on ONE XCD:
//   r=id/96 (0..31), G=id%96 ; id%8 == G%8 for all r since 96%8==0.
// Output yg written as bf16 (consumed by bf16 out-proj GEMM).
// ---------------------------------------------------------------------------
#define SCAN_T  32
#define SCAN_NC 16
__global__ __launch_bounds__(256) void scan_kernel2(
    const float* __restrict__ xs,     // M x 768 (u)
    const float* __restrict__ delta,  // M x 768
    const float* __restrict__ xdbl,   // M x 56 (dt|B|C)
    const float* __restrict__ A_log,  // 768 x 16 (layer slice)
    const float* __restrict__ Dp,     // 768
    const float* __restrict__ xr,     // M x 1536 (res = cols 768..)
    __hip_bfloat16* __restrict__ yg)  // M x 768 bf16
{
  __shared__ float sdelta[LL];
  __shared__ float su[LL];
  __shared__ float sP[SCAN_NC][D_STATE];
  __shared__ float sS[SCAN_NC][D_STATE];
  __shared__ float sH0[SCAN_NC][D_STATE];

  const int id = blockIdx.x;
  const int r  = id / 96;        // 0..31
  const int G  = id % 96;        // 0..95
  const int b  = G / 24;         // 0..3
  const int d  = (G % 24) * 32 + r;

  const int tid = threadIdx.x;
  const int n = tid & 15;
  const int c = tid >> 4;

  for (int l = tid; l < LL; l += 256) {
    size_t m = (size_t)(b * LL + l);
    sdelta[l] = delta[m * D_INNER + d];
    su[l]     = xs[m * D_INNER + d];
  }

  const float Aval = -__expf(A_log[d * D_STATE + n]);
  __syncthreads();

  // Phase 1: per-chunk affine composition (P, S)
  {
    float P = 1.f, S = 0.f;
    const int l0 = c * SCAN_T;
    #pragma unroll 4
    for (int t = 0; t < SCAN_T; ++t) {
      int l = l0 + t;
      size_t m = (size_t)(b * LL + l);
      float dv = sdelta[l];
      float uv = su[l];
      float Bv = xdbl[m * 56 + DT_RANK + n];
      float a = __expf(dv * Aval);
      P *= a;
      S = a * S + (dv * Bv) * uv;
    }
    sP[c][n] = P;
    sS[c][n] = S;
  }
  __syncthreads();

  // Phase 2: serial compose across chunks
  if (tid < D_STATE) {
    float h = 0.f;
    #pragma unroll
    for (int cc = 0; cc < SCAN_NC; ++cc) {
      sH0[cc][tid] = h;
      h = sP[cc][tid] * h + sS[cc][tid];
    }
  }
  __syncthreads();

  // Phase 3: replay from entry state, emit gated bf16 output
  {
    const float Dv = Dp[d];
    float h = sH0[c][n];
    const int l0 = c * SCAN_T;
    #pragma unroll 4
    for (int t = 0; t < SCAN_T; ++t) {
      int l = l0 + t;
      size_t m = (size_t)(b * LL + l);
      float dv = sdelta[l];
      float uv = su[l];
      float Bv = xdbl[m * 56 + DT_RANK + n];
      float Cv = xdbl[m * 56 + DT_RANK + D_STATE + n];
      float a = __expf(dv * Aval);
      h = a * h + (dv * Bv) * uv;
      float contrib = h * Cv;
      contrib += __shfl_xor(contrib, 1, 64);
      contrib += __shfl_xor(contrib, 2, 64);
      contrib += __shfl_xor(contrib, 4, 64);
      contrib += __shfl_xor(contrib, 8, 64);
      if (n == 0) {
        float y = contrib + uv * Dv;
        float rres = xr[m * (2 * D_INNER) + D_INNER + d];
        yg[m * D_INNER + d] = __float2bfloat16(y * silu_f(rres));
      }
    }
  }
}

// ---------------------------------------------------------------------------
// Attention: out[b,q,:] = softmax_k(h[b,q,:]·enc[b,k,:]) @ enc[b]
// ---------------------------------------------------------------------------
#define TQ 8
__global__ __launch_bounds__(512) void attn_kernel(
    const float* __restrict__ h, const float* __restrict__ enc,
    float* __restrict__ out)
{
  __shared__ float hrow[TQ][D_MODEL];
  __shared__ float p[TQ][LL];
  int blk = blockIdx.x;
  int b = blk / (LL / TQ);
  int q0 = (blk % (LL / TQ)) * TQ;
  int tid = threadIdx.x;

  for (int i = tid; i < TQ * D_MODEL; i += 512) {
    int qi = i / D_MODEL, j = i - qi * D_MODEL;
    hrow[qi][j] = h[((size_t)b * LL + q0 + qi) * D_MODEL + j];
  }
  __syncthreads();

  {
    int k = tid;
    const float* er = enc + ((size_t)b * LL + k) * D_MODEL;
    float acc[TQ] = {};
    for (int j = 0; j < D_MODEL; ++j) {
      float e = er[j];
      #pragma unroll
      for (int qi = 0; qi < TQ; ++qi) acc[qi] += hrow[qi][j] * e;
    }
    #pragma unroll
    for (int qi = 0; qi < TQ; ++qi) p[qi][k] = acc[qi];
  }
  __syncthreads();

  {
    int w = tid >> 6, lane = tid & 63;
    float mx = -1e30f;
    for (int k = lane; k < LL; k += 64) mx = fmaxf(mx, p[w][k]);
    #pragma unroll
    for (int off = 32; off; off >>= 1) mx = fmaxf(mx, __shfl_xor(mx, off, 64));
    float sum = 0.f;
    for (int k = lane; k < LL; k += 64) { float e = __expf(p[w][k] - mx); p[w][k] = e; sum += e; }
    #pragma unroll
    for (int off = 32; off; off >>= 1) sum += __shfl_xor(sum, off, 64);
    float inv = 1.f / sum;
    for (int k = lane; k < LL; k += 64) p[w][k] *= inv;
  }
  __syncthreads();

  if (tid < D_MODEL) {
    int d = tid;
    float acc[TQ] = {};
    for (int k = 0; k < LL; ++k) {
      float e = enc[((size_t)b * LL + k) * D_MODEL + d];
      #pragma unroll
      for (int qi = 0; qi < TQ; ++qi) acc[qi] += p[qi][k] * e;
    }
    #pragma unroll
    for (int qi = 0; qi < TQ; ++qi)
      out[((size_t)b * LL + q0 + qi) * D_MODEL + d] = acc[qi];
  }
}

// ---------------------------------------------------------------------------
extern "C" void kernel_launch(void* const* d_in, const int* in_sizes, int n_in,
                              void* d_out, int out_size, void* d_ws, size_t ws_size,
                              hipStream_t stream) {
  const float* x        = (const float*)d_in[0];
  const float* enc      = (const float*)d_in[1];
  const float* w_in     = (const float*)d_in[2];
  const float* b_in     = (const float*)d_in[3];
  const float* ln_w     = (const float*)d_in[4];
  const float* inproj_w = (const float*)d_in[5];
  const float* conv_w   = (const float*)d_in[6];
  const float* conv_b   = (const float*)d_in[7];
  const float* xproj_w  = (const float*)d_in[8];
  const float* dtproj_w = (const float*)d_in[9];
  const float* dtproj_b = (const float*)d_in[10];
  const float* A_log    = (const float*)d_in[11];
  const float* Dvec     = (const float*)d_in[12];
  const float* outproj_w= (const float*)d_in[13];
  const float* normf_w  = (const float*)d_in[14];
  const float* w_out    = (const float*)d_in[15];

  float* ws = (float*)d_ws;
  float* h    = ws; ws += MTOK * D_MODEL;
  float* hn   = ws; ws += MTOK * D_MODEL;
  float* xr   = ws; ws += MTOK * 2 * D_INNER;
  float* xs   = ws; ws += MTOK * D_INNER;
  float* xdbl = ws; ws += MTOK * 56;
  float* delta= ws; ws += MTOK * D_INNER;
  float* h2   = ws; ws += MTOK * D_MODEL;
  __hip_bfloat16* hn_bf = (__hip_bfloat16*)ws; ws += MTOK * D_MODEL / 2;
  __hip_bfloat16* yg_bf = (__hip_bfloat16*)ws; ws += MTOK * D_INNER / 2;
  __hip_bfloat16* WinT  = (__hip_bfloat16*)ws; ws += N_LAYER * D_MODEL * 2 * D_INNER / 2;
  __hip_bfloat16* WoutT = (__hip_bfloat16*)ws; ws += N_LAYER * D_INNER * D_MODEL / 2;

  dim3 blk256(256), blk512(512);

  // Prologue: convert+transpose big weights to bf16 [N][K]
  wconv_t_kernel<<<dim3(2 * D_INNER / 32, D_MODEL / 32, N_LAYER), blk256, 0, stream>>>(
      inproj_w, WinT, D_MODEL, 2 * D_INNER);
  wconv_t_kernel<<<dim3(D_MODEL / 32, D_INNER / 32, N_LAYER), blk256, 0, stream>>>(
      outproj_w, WoutT, D_INNER, D_MODEL);

  // input projection: h = x @ w_in + b_in  (fp32)
  gemm_f32<1><<<dim3(D_MODEL / BNt, MTOK / BMt), blk256, 0, stream>>>(
      x, N_MELS, w_in, D_MODEL, b_in, nullptr, h, D_MODEL, MTOK, D_MODEL, N_MELS);

  auto mamba = [&](float* hcur, int i) {
    rmsnorm_kernel<<<MTOK * 64 / 256, blk256, 0, stream>>>(
        hcur, ln_w + (size_t)i * D_MODEL, hn, hn_bf, MTOK, D_MODEL);
    // in-proj (bf16 MFMA): xr = hn @ inproj_w
    gemm_bf16<0><<<dim3(2 * D_INNER / 64, MTOK / 64), blk256, 0, stream>>>(
        hn_bf, WinT + (size_t)i * D_MODEL * 2 * D_INNER, nullptr,
        xr, 2 * D_INNER, MTOK, 2 * D_INNER, D_MODEL);
    conv_silu_kernel<<<MTOK * D_INNER / 256, blk256, 0, stream>>>(
        xr, conv_w + (size_t)i * D_INNER * D_CONV, conv_b + (size_t)i * D_INNER, xs);
    gemm_f32<0><<<dim3(1, MTOK / BMt), blk256, 0, stream>>>(
        xs, D_INNER, xproj_w + (size_t)i * D_INNER * 56, 56,
        nullptr, nullptr, xdbl, 56, MTOK, 56, D_INNER);
    gemm_f32<2><<<dim3(D_INNER / BNt, MTOK / BMt), blk256, 0, stream>>>(
        xdbl, 56, dtproj_w + (size_t)i * DT_RANK * D_INNER, D_INNER,
        dtproj_b + (size_t)i * D_INNER, nullptr, delta, D_INNER, MTOK, D_INNER, DT_RANK);
    scan_kernel2<<<BB * D_INNER / 32 * 32, blk256, 0, stream>>>(
        xs, delta, xdbl, A_log + (size_t)i * D_INNER * D_STATE,
        Dvec + (size_t)i * D_INNER, xr, yg_bf);
    // out-proj (bf16 MFMA) + residual: hcur += yg @ outproj_w
    gemm_bf16<3><<<dim3(D_MODEL / 64, MTOK / 64), blk256, 0, stream>>>(
        yg_bf, WoutT + (size_t)i * D_INNER * D_MODEL, hcur,
        hcur, D_MODEL, MTOK, D_MODEL, D_INNER);
  };

  for (int i = 0; i < N_LAYER / 2; ++i) mamba(h, i);

  attn_kernel<<<MTOK / TQ, blk512, 0, stream>>>(h, enc, h2);

  for (int i = N_LAYER / 2; i < N_LAYER; ++i) mamba(h2, i);

  rmsnorm_kernel<<<MTOK * 64 / 256, blk256, 0, stream>>>(h2, normf_w, hn, hn_bf, MTOK, D_MODEL);
  gemm_f32<0><<<dim3((N_MELS + BNt - 1) / BNt, MTOK / BMt), blk256, 0, stream>>>(
      hn, D_MODEL, w_out, N_MELS, nullptr, nullptr, (float*)d_out, N_MELS, MTOK, N_MELS, D_MODEL);
}

// Round 6
// 1036.069 us; speedup vs baseline: 4.4460x; 1.4114x over previous
//
#include <hip/hip_runtime.h>
#include <hip/hip_bf16.h>
#include <math.h>

// Problem dims (fixed by reference)
#define D_MODEL 384
#define N_LAYER 8
#define N_MELS  80
#define D_STATE 16
#define D_CONV  4
#define D_INNER 768
#define DT_RANK 24
#define BB      4
#define LL      512
#define MTOK    (BB*LL)   // 2048

#define BMt 64
#define BNt 64
#define BKt 16

#define XP_N    56
#define XP_SPLIT 8
#define XP_KC   (D_INNER / XP_SPLIT)   // 96

typedef __attribute__((ext_vector_type(8))) short bf16x8;
typedef __attribute__((ext_vector_type(4))) float f32x4;

__device__ __forceinline__ float silu_f(float x) { return x / (1.f + __expf(-x)); }

// ---------------------------------------------------------------------------
// Generic tiled fp32 GEMM (edge ops only): C[M,N] = A[M,K] @ W[K,N]
// EPI: 0 none, 1 +bias
// ---------------------------------------------------------------------------
template<int EPI>
__global__ __launch_bounds__(256) void gemm_f32(
    const float* __restrict__ A, int lda,
    const float* __restrict__ W, int ldw,
    const float* __restrict__ bias,
    float* __restrict__ C, int ldc,
    int M, int N, int K)
{
  __shared__ float As[BKt][BMt];   // [k][m]
  __shared__ float Ws[BKt][BNt];   // [k][n]
  const int tid = threadIdx.x;
  const int tx = tid & 15, ty = tid >> 4;
  const int m0 = blockIdx.y * BMt, n0 = blockIdx.x * BNt;
  const int am = tid >> 2, ak4 = (tid & 3) << 2;
  const int wk = tid >> 4, wn4 = (tid & 15) << 2;

  float acc[4][4] = {};

  for (int k0 = 0; k0 < K; k0 += BKt) {
    float4 va = make_float4(0.f, 0.f, 0.f, 0.f);
    {
      int m = m0 + am;
      if (m < M) {
        if (k0 + ak4 + 3 < K) {
          va = *reinterpret_cast<const float4*>(&A[(size_t)m * lda + k0 + ak4]);
        } else {
          float t[4];
          #pragma unroll
          for (int j = 0; j < 4; ++j)
            t[j] = (k0 + ak4 + j < K) ? A[(size_t)m * lda + k0 + ak4 + j] : 0.f;
          va = make_float4(t[0], t[1], t[2], t[3]);
        }
      }
    }
    As[ak4 + 0][am] = va.x;
    As[ak4 + 1][am] = va.y;
    As[ak4 + 2][am] = va.z;
    As[ak4 + 3][am] = va.w;

    float4 vw = make_float4(0.f, 0.f, 0.f, 0.f);
    {
      int kw = k0 + wk;
      if (kw < K) {
        if (n0 + wn4 + 3 < N) {
          vw = *reinterpret_cast<const float4*>(&W[(size_t)kw * ldw + n0 + wn4]);
        } else {
          float t[4];
          #pragma unroll
          for (int j = 0; j < 4; ++j)
            t[j] = (n0 + wn4 + j < N) ? W[(size_t)kw * ldw + n0 + wn4 + j] : 0.f;
          vw = make_float4(t[0], t[1], t[2], t[3]);
        }
      }
    }
    *reinterpret_cast<float4*>(&Ws[wk][wn4]) = vw;

    __syncthreads();
    #pragma unroll
    for (int kk = 0; kk < BKt; ++kk) {
      const float4 a4 = *reinterpret_cast<const float4*>(&As[kk][ty << 2]);
      const float4 w4 = *reinterpret_cast<const float4*>(&Ws[kk][tx << 2]);
      float av[4] = {a4.x, a4.y, a4.z, a4.w};
      float wv[4] = {w4.x, w4.y, w4.z, w4.w};
      #pragma unroll
      for (int i = 0; i < 4; ++i)
        #pragma unroll
        for (int j = 0; j < 4; ++j)
          acc[i][j] += av[i] * wv[j];
    }
    __syncthreads();
  }

  #pragma unroll
  for (int i = 0; i < 4; ++i) {
    int row = m0 + (ty << 2) + i;
    if (row >= M) continue;
    #pragma unroll
    for (int j = 0; j < 4; ++j) {
      int col = n0 + (tx << 2) + j;
      if (col >= N) continue;
      float v = acc[i][j];
      if (EPI == 1) v += bias[col];
      C[(size_t)row * ldc + col] = v;
    }
  }
}

// ---------------------------------------------------------------------------
// Split-K x-proj: part[s][M][56] = xs[:, s*96:(s+1)*96] @ xp[s*96:(s+1)*96, :]
// Grid: (XP_SPLIT, M/64). Fixes the 32-block occupancy disaster (1.3% -> full).
// ---------------------------------------------------------------------------
__global__ __launch_bounds__(256) void xproj_splitk_kernel(
    const float* __restrict__ A,   // [M][768] = xs
    const float* __restrict__ W,   // [768][56] layer slice
    float* __restrict__ part)      // [XP_SPLIT][M][56]
{
  __shared__ float As[BKt][BMt];
  __shared__ float Ws[BKt][BNt];
  const int tid = threadIdx.x;
  const int tx = tid & 15, ty = tid >> 4;
  const int split = blockIdx.x;
  const int m0 = blockIdx.y * BMt;
  const int am = tid >> 2, ak4 = (tid & 3) << 2;
  const int wk = tid >> 4, wn4 = (tid & 15) << 2;
  const int kbase = split * XP_KC;

  float acc[4][4] = {};

  for (int k0 = 0; k0 < XP_KC; k0 += BKt) {
    float4 va = *reinterpret_cast<const float4*>(
        &A[(size_t)(m0 + am) * D_INNER + kbase + k0 + ak4]);
    As[ak4 + 0][am] = va.x;
    As[ak4 + 1][am] = va.y;
    As[ak4 + 2][am] = va.z;
    As[ak4 + 3][am] = va.w;

    float4 vw = make_float4(0.f, 0.f, 0.f, 0.f);
    if (wn4 < XP_N)   // wn4 in {0..60}; 56,60 are out of range (rows are 56 floats, 16B-aligned: 224B)
      vw = *reinterpret_cast<const float4*>(&W[(size_t)(kbase + k0 + wk) * XP_N + wn4]);
    *reinterpret_cast<float4*>(&Ws[wk][wn4]) = vw;

    __syncthreads();
    #pragma unroll
    for (int kk = 0; kk < BKt; ++kk) {
      const float4 a4 = *reinterpret_cast<const float4*>(&As[kk][ty << 2]);
      const float4 w4 = *reinterpret_cast<const float4*>(&Ws[kk][tx << 2]);
      float av[4] = {a4.x, a4.y, a4.z, a4.w};
      float wv[4] = {w4.x, w4.y, w4.z, w4.w};
      #pragma unroll
      for (int i = 0; i < 4; ++i)
        #pragma unroll
        for (int j = 0; j < 4; ++j)
          acc[i][j] += av[i] * wv[j];
    }
    __syncthreads();
  }

  #pragma unroll
  for (int i = 0; i < 4; ++i) {
    int row = m0 + (ty << 2) + i;
    #pragma unroll
    for (int j = 0; j < 4; ++j) {
      int col = (tx << 2) + j;
      if (col < XP_N)
        part[((size_t)split * MTOK + row) * XP_N + col] = acc[i][j];
    }
  }
}

__global__ __launch_bounds__(256) void xproj_reduce_kernel(
    const float* __restrict__ part, float* __restrict__ xdbl)
{
  int idx = blockIdx.x * 256 + threadIdx.x;
  if (idx >= MTOK * XP_N) return;
  float s = 0.f;
  #pragma unroll
  for (int p = 0; p < XP_SPLIT; ++p)
    s += part[(size_t)p * MTOK * XP_N + idx];
  xdbl[idx] = s;
}

// ---------------------------------------------------------------------------
// bf16 MFMA GEMM: C_f32[M,N] = A_bf16[M,K] @ WT_bf16[N,K]   (WT pre-transposed)
// EPI: 0 none, 3 +resid. M,N,K multiples of 64.
// ---------------------------------------------------------------------------
template<int EPI>
__global__ __launch_bounds__(256) void gemm_bf16(
    const __hip_bfloat16* __restrict__ A,   // [M][K]
    const __hip_bfloat16* __restrict__ WT,  // [N][K]
    const float* __restrict__ resid,
    float* __restrict__ C, int ldc,
    int M, int N, int K)
{
  __shared__ __align__(16) __hip_bfloat16 Asl[64][72];
  __shared__ __align__(16) __hip_bfloat16 Bsl[64][72];
  const int tid = threadIdx.x;
  const int wave = tid >> 6, lane = tid & 63;
  const int m0 = blockIdx.y * 64, n0 = blockIdx.x * 64;
  const int lrow = tid >> 2;
  const int lk   = (tid & 3) << 4;
  const int g16 = lane >> 4;
  const int l16 = lane & 15;

  f32x4 acc[4] = {};

  for (int k0 = 0; k0 < K; k0 += 64) {
    const uint4* ga = reinterpret_cast<const uint4*>(&A[(size_t)(m0 + lrow) * K + k0 + lk]);
    uint4* la = reinterpret_cast<uint4*>(&Asl[lrow][lk]);
    la[0] = ga[0]; la[1] = ga[1];
    const uint4* gb = reinterpret_cast<const uint4*>(&WT[(size_t)(n0 + lrow) * K + k0 + lk]);
    uint4* lb = reinterpret_cast<uint4*>(&Bsl[lrow][lk]);
    lb[0] = gb[0]; lb[1] = gb[1];
    __syncthreads();
    #pragma unroll
    for (int kk = 0; kk < 64; kk += 32) {
      bf16x8 a = *reinterpret_cast<const bf16x8*>(&Asl[wave * 16 + l16][kk + g16 * 8]);
      #pragma unroll
      for (int f = 0; f < 4; ++f) {
        bf16x8 b = *reinterpret_cast<const bf16x8*>(&Bsl[f * 16 + l16][kk + g16 * 8]);
        acc[f] = __builtin_amdgcn_mfma_f32_16x16x32_bf16(a, b, acc[f], 0, 0, 0);
      }
    }
    __syncthreads();
  }

  #pragma unroll
  for (int f = 0; f < 4; ++f) {
    #pragma unroll
    for (int r = 0; r < 4; ++r) {
      int row = m0 + wave * 16 + g16 * 4 + r;
      int col = n0 + f * 16 + l16;
      float v = acc[f][r];
      if (EPI == 3) v += resid[(size_t)row * ldc + col];
      C[(size_t)row * ldc + col] = v;
    }
  }
}

// ---------------------------------------------------------------------------
// Weight convert + transpose: src f32 [L][K][N] -> dst bf16 [L][N][K]
// ---------------------------------------------------------------------------
__global__ __launch_bounds__(256) void wconv_t_kernel(
    const float* __restrict__ src, __hip_bfloat16* __restrict__ dst,
    int K, int N)
{
  __shared__ float tile[32][33];
  int l = blockIdx.z;
  int kb = blockIdx.y * 32, nb = blockIdx.x * 32;
  int tn = threadIdx.x & 31, tk = threadIdx.x >> 5;  // 32 x 8
  const float* s = src + (size_t)l * K * N;
  __hip_bfloat16* dd = dst + (size_t)l * N * K;
  #pragma unroll
  for (int i = 0; i < 4; ++i) {
    int k = kb + tk + i * 8, n = nb + tn;
    tile[tk + i * 8][tn] = (k < K && n < N) ? s[(size_t)k * N + n] : 0.f;
  }
  __syncthreads();
  #pragma unroll
  for (int i = 0; i < 4; ++i) {
    int n = nb + tk + i * 8, k = kb + tn;
    if (n < N && k < K) dd[(size_t)n * K + k] = __float2bfloat16(tile[tn][tk + i * 8]);
  }
}

// ---------------------------------------------------------------------------
// RMSNorm: one wave per row; writes fp32 and bf16 copies
// ---------------------------------------------------------------------------
__global__ __launch_bounds__(256) void rmsnorm_kernel(
    const float* __restrict__ x, const float* __restrict__ w,
    float* __restrict__ out, __hip_bfloat16* __restrict__ outb, int M, int N)
{
  int gw = (blockIdx.x * blockDim.x + threadIdx.x) >> 6;
  int lane = threadIdx.x & 63;
  if (gw >= M) return;
  const float* row = x + (size_t)gw * N;
  float ss = 0.f;
  for (int j = lane; j < N; j += 64) { float v = row[j]; ss += v * v; }
  #pragma unroll
  for (int off = 32; off; off >>= 1) ss += __shfl_xor(ss, off, 64);
  float scale = rsqrtf(ss / (float)N + 1e-5f);
  float* orow = out + (size_t)gw * N;
  __hip_bfloat16* brow = outb + (size_t)gw * N;
  for (int j = lane; j < N; j += 64) {
    float v = row[j] * scale * w[j];
    orow[j] = v;
    brow[j] = __float2bfloat16(v);
  }
}

// ---------------------------------------------------------------------------
// Depthwise causal conv (k=4) + bias + SiLU.
// ---------------------------------------------------------------------------
__global__ __launch_bounds__(256) void conv_silu_kernel(
    const float* __restrict__ xr, const float* __restrict__ cw,
    const float* __restrict__ cb, float* __restrict__ xs)
{
  int idx = blockIdx.x * 256 + threadIdx.x;
  if (idx >= MTOK * D_INNER) return;
  int m = idx / D_INNER;
  int d = idx - m * D_INNER;
  int b = m >> 9, l = m & 511;
  float acc = 0.f;
  #pragma unroll
  for (int k = 0; k < D_CONV; ++k) {
    int t = l - (D_CONV - 1) + k;
    if (t >= 0) acc += xr[((size_t)(b * LL + t)) * (2 * D_INNER) + d] * cw[d * D_CONV + k];
  }
  acc += cb[d];
  xs[idx] = silu_f(acc);
}

// ---------------------------------------------------------------------------
// Chunked parallel selective scan, XCD-swizzled blocks, dt-proj FUSED.
// delta[:,d] = softplus(xdbl[:, :24] @ dw[:,d] + db[d]) computed during
// LDS staging (24 FMAs/step from L2-resident xdbl) -- kills the dt-proj
// GEMM dispatch and the 12.6MB/layer delta buffer round-trip.
// ---------------------------------------------------------------------------
#define SCAN_T  32
#define SCAN_NC 16
__global__ __launch_bounds__(256) void scan_kernel2(
    const float* __restrict__ xs,     // M x 768 (u)
    const float* __restrict__ xdbl,   // M x 56 (dt|B|C)
    const float* __restrict__ A_log,  // 768 x 16 (layer slice)
    const float* __restrict__ Dp,     // 768
    const float* __restrict__ dtw,    // [24][768] layer slice
    const float* __restrict__ dtb,    // [768] layer slice
    const float* __restrict__ xr,     // M x 1536 (res = cols 768..)
    __hip_bfloat16* __restrict__ yg)  // M x 768 bf16
{
  __shared__ float sdelta[LL];
  __shared__ float su[LL];
  __shared__ float sdw[DT_RANK];
  __shared__ float sP[SCAN_NC][D_STATE];
  __shared__ float sS[SCAN_NC][D_STATE];
  __shared__ float sH0[SCAN_NC][D_STATE];

  const int id = blockIdx.x;
  const int r  = id / 96;        // 0..31
  const int G  = id % 96;        // 0..95   (id%8 == G%8 -> same-line d's share an XCD)
  const int b  = G / 24;         // 0..3
  const int d  = (G % 24) * 32 + r;

  const int tid = threadIdx.x;
  const int n = tid & 15;
  const int c = tid >> 4;

  if (tid < DT_RANK) sdw[tid] = dtw[tid * D_INNER + d];
  __syncthreads();

  const float dtb_d = dtb[d];
  for (int l = tid; l < LL; l += 256) {
    size_t m = (size_t)(b * LL + l);
    float acc = dtb_d;
    #pragma unroll
    for (int k = 0; k < DT_RANK; ++k)
      acc += xdbl[m * 56 + k] * sdw[k];
    sdelta[l] = (acc > 20.f) ? acc : log1pf(__expf(acc));
    su[l]     = xs[m * D_INNER + d];
  }

  const float Aval = -__expf(A_log[d * D_STATE + n]);
  __syncthreads();

  // Phase 1: per-chunk affine composition (P, S)
  {
    float P = 1.f, S = 0.f;
    const int l0 = c * SCAN_T;
    #pragma unroll 4
    for (int t = 0; t < SCAN_T; ++t) {
      int l = l0 + t;
      size_t m = (size_t)(b * LL + l);
      float dv = sdelta[l];
      float uv = su[l];
      float Bv = xdbl[m * 56 + DT_RANK + n];
      float a = __expf(dv * Aval);
      P *= a;
      S = a * S + (dv * Bv) * uv;
    }
    sP[c][n] = P;
    sS[c][n] = S;
  }
  __syncthreads();

  // Phase 2: serial compose across chunks
  if (tid < D_STATE) {
    float h = 0.f;
    #pragma unroll
    for (int cc = 0; cc < SCAN_NC; ++cc) {
      sH0[cc][tid] = h;
      h = sP[cc][tid] * h + sS[cc][tid];
    }
  }
  __syncthreads();

  // Phase 3: replay from entry state, emit gated bf16 output
  {
    const float Dv = Dp[d];
    float h = sH0[c][n];
    const int l0 = c * SCAN_T;
    #pragma unroll 4
    for (int t = 0; t < SCAN_T; ++t) {
      int l = l0 + t;
      size_t m = (size_t)(b * LL + l);
      float dv = sdelta[l];
      float uv = su[l];
      float Bv = xdbl[m * 56 + DT_RANK + n];
      float Cv = xdbl[m * 56 + DT_RANK + D_STATE + n];
      float a = __expf(dv * Aval);
      h = a * h + (dv * Bv) * uv;
      float contrib = h * Cv;
      contrib += __shfl_xor(contrib, 1, 64);
      contrib += __shfl_xor(contrib, 2, 64);
      contrib += __shfl_xor(contrib, 4, 64);
      contrib += __shfl_xor(contrib, 8, 64);
      if (n == 0) {
        float y = contrib + uv * Dv;
        float rres = xr[m * (2 * D_INNER) + D_INNER + d];
        yg[m * D_INNER + d] = __float2bfloat16(y * silu_f(rres));
      }
    }
  }
}

// ---------------------------------------------------------------------------
// Attention: out[b,q,:] = softmax_k(h[b,q,:]·enc[b,k,:]) @ enc[b]
// ---------------------------------------------------------------------------
#define TQ 8
__global__ __launch_bounds__(512) void attn_kernel(
    const float* __restrict__ h, const float* __restrict__ enc,
    float* __restrict__ out)
{
  __shared__ float hrow[TQ][D_MODEL];
  __shared__ float p[TQ][LL];
  int blk = blockIdx.x;
  int b = blk / (LL / TQ);
  int q0 = (blk % (LL / TQ)) * TQ;
  int tid = threadIdx.x;

  for (int i = tid; i < TQ * D_MODEL; i += 512) {
    int qi = i / D_MODEL, j = i - qi * D_MODEL;
    hrow[qi][j] = h[((size_t)b * LL + q0 + qi) * D_MODEL + j];
  }
  __syncthreads();

  {
    int k = tid;
    const float* er = enc + ((size_t)b * LL + k) * D_MODEL;
    float acc[TQ] = {};
    for (int j = 0; j < D_MODEL; ++j) {
      float e = er[j];
      #pragma unroll
      for (int qi = 0; qi < TQ; ++qi) acc[qi] += hrow[qi][j] * e;
    }
    #pragma unroll
    for (int qi = 0; qi < TQ; ++qi) p[qi][k] = acc[qi];
  }
  __syncthreads();

  {
    int w = tid >> 6, lane = tid & 63;
    float mx = -1e30f;
    for (int k = lane; k < LL; k += 64) mx = fmaxf(mx, p[w][k]);
    #pragma unroll
    for (int off = 32; off; off >>= 1) mx = fmaxf(mx, __shfl_xor(mx, off, 64));
    float sum = 0.f;
    for (int k = lane; k < LL; k += 64) { float e = __expf(p[w][k] - mx); p[w][k] = e; sum += e; }
    #pragma unroll
    for (int off = 32; off; off >>= 1) sum += __shfl_xor(sum, off, 64);
    float inv = 1.f / sum;
    for (int k = lane; k < LL; k += 64) p[w][k] *= inv;
  }
  __syncthreads();

  if (tid < D_MODEL) {
    int d = tid;
    float acc[TQ] = {};
    for (int k = 0; k < LL; ++k) {
      float e = enc[((size_t)b * LL + k) * D_MODEL + d];
      #pragma unroll
      for (int qi = 0; qi < TQ; ++qi) acc[qi] += p[qi][k] * e;
    }
    #pragma unroll
    for (int qi = 0; qi < TQ; ++qi)
      out[((size_t)b * LL + q0 + qi) * D_MODEL + d] = acc[qi];
  }
}

// ---------------------------------------------------------------------------
extern "C" void kernel_launch(void* const* d_in, const int* in_sizes, int n_in,
                              void* d_out, int out_size, void* d_ws, size_t ws_size,
                              hipStream_t stream) {
  const float* x        = (const float*)d_in[0];
  const float* enc      = (const float*)d_in[1];
  const float* w_in     = (const float*)d_in[2];
  const float* b_in     = (const float*)d_in[3];
  const float* ln_w     = (const float*)d_in[4];
  const float* inproj_w = (const float*)d_in[5];
  const float* conv_w   = (const float*)d_in[6];
  const float* conv_b   = (const float*)d_in[7];
  const float* xproj_w  = (const float*)d_in[8];
  const float* dtproj_w = (const float*)d_in[9];
  const float* dtproj_b = (const float*)d_in[10];
  const float* A_log    = (const float*)d_in[11];
  const float* Dvec     = (const float*)d_in[12];
  const float* outproj_w= (const float*)d_in[13];
  const float* normf_w  = (const float*)d_in[14];
  const float* w_out    = (const float*)d_in[15];

  float* ws = (float*)d_ws;
  float* h     = ws; ws += MTOK * D_MODEL;
  float* hn    = ws; ws += MTOK * D_MODEL;
  float* xr    = ws; ws += MTOK * 2 * D_INNER;
  float* xs    = ws; ws += MTOK * D_INNER;
  float* xdbl  = ws; ws += MTOK * XP_N;
  float* xpart = ws; ws += XP_SPLIT * MTOK * XP_N;
  float* h2    = ws; ws += MTOK * D_MODEL;
  __hip_bfloat16* hn_bf = (__hip_bfloat16*)ws; ws += MTOK * D_MODEL / 2;
  __hip_bfloat16* yg_bf = (__hip_bfloat16*)ws; ws += MTOK * D_INNER / 2;
  __hip_bfloat16* WinT  = (__hip_bfloat16*)ws; ws += N_LAYER * D_MODEL * 2 * D_INNER / 2;
  __hip_bfloat16* WoutT = (__hip_bfloat16*)ws; ws += N_LAYER * D_INNER * D_MODEL / 2;

  dim3 blk256(256), blk512(512);

  // Prologue: convert+transpose big weights to bf16 [N][K]
  wconv_t_kernel<<<dim3(2 * D_INNER / 32, D_MODEL / 32, N_LAYER), blk256, 0, stream>>>(
      inproj_w, WinT, D_MODEL, 2 * D_INNER);
  wconv_t_kernel<<<dim3(D_MODEL / 32, D_INNER / 32, N_LAYER), blk256, 0, stream>>>(
      outproj_w, WoutT, D_INNER, D_MODEL);

  // input projection: h = x @ w_in + b_in  (fp32)
  gemm_f32<1><<<dim3(D_MODEL / BNt, MTOK / BMt), blk256, 0, stream>>>(
      x, N_MELS, w_in, D_MODEL, b_in, h, D_MODEL, MTOK, D_MODEL, N_MELS);

  auto mamba = [&](float* hcur, int i) {
    rmsnorm_kernel<<<MTOK * 64 / 256, blk256, 0, stream>>>(
        hcur, ln_w + (size_t)i * D_MODEL, hn, hn_bf, MTOK, D_MODEL);
    // in-proj (bf16 MFMA): xr = hn @ inproj_w
    gemm_bf16<0><<<dim3(2 * D_INNER / 64, MTOK / 64), blk256, 0, stream>>>(
        hn_bf, WinT + (size_t)i * D_MODEL * 2 * D_INNER, nullptr,
        xr, 2 * D_INNER, MTOK, 2 * D_INNER, D_MODEL);
    conv_silu_kernel<<<MTOK * D_INNER / 256, blk256, 0, stream>>>(
        xr, conv_w + (size_t)i * D_INNER * D_CONV, conv_b + (size_t)i * D_INNER, xs);
    // x-proj split-K + reduce
    xproj_splitk_kernel<<<dim3(XP_SPLIT, MTOK / BMt), blk256, 0, stream>>>(
        xs, xproj_w + (size_t)i * D_INNER * XP_N, xpart);
    xproj_reduce_kernel<<<(MTOK * XP_N + 255) / 256, blk256, 0, stream>>>(xpart, xdbl);
    // scan (dt-proj fused)
    scan_kernel2<<<BB * D_INNER, blk256, 0, stream>>>(
        xs, xdbl, A_log + (size_t)i * D_INNER * D_STATE, Dvec + (size_t)i * D_INNER,
        dtproj_w + (size_t)i * DT_RANK * D_INNER, dtproj_b + (size_t)i * D_INNER,
        xr, yg_bf);
    // out-proj (bf16 MFMA) + residual: hcur += yg @ outproj_w
    gemm_bf16<3><<<dim3(D_MODEL / 64, MTOK / 64), blk256, 0, stream>>>(
        yg_bf, WoutT + (size_t)i * D_INNER * D_MODEL, hcur,
        hcur, D_MODEL, MTOK, D_MODEL, D_INNER);
  };

  for (int i = 0; i < N_LAYER / 2; ++i) mamba(h, i);

  attn_kernel<<<MTOK / TQ, blk512, 0, stream>>>(h, enc, h2);

  for (int i = N_LAYER / 2; i < N_LAYER; ++i) mamba(h2, i);

  rmsnorm_kernel<<<MTOK * 64 / 256, blk256, 0, stream>>>(h2, normf_w, hn, hn_bf, MTOK, D_MODEL);
  gemm_f32<0><<<dim3((N_MELS + BNt - 1) / BNt, MTOK / BMt), blk256, 0, stream>>>(
      hn, D_MODEL, w_out, N_MELS, nullptr, (float*)d_out, N_MELS, MTOK, N_MELS, D_MODEL);
}

// Round 7
// 990.978 us; speedup vs baseline: 4.6483x; 1.0455x over previous
//
#include <hip/hip_runtime.h>
#include <hip/hip_bf16.h>
#include <math.h>

// Problem dims (fixed by reference)
#define D_MODEL 384
#define N_LAYER 8
#define N_MELS  80
#define D_STATE 16
#define D_CONV  4
#define D_INNER 768
#define DT_RANK 24
#define BB      4
#define LL      512
#define MTOK    (BB*LL)   // 2048

#define BMt 64
#define BNt 64
#define BKt 16

#define XP_N    56
#define XP_SPLIT 8
#define XP_KC   (D_INNER / XP_SPLIT)   // 96

typedef __attribute__((ext_vector_type(8))) short bf16x8;
typedef __attribute__((ext_vector_type(4))) float f32x4;

__device__ __forceinline__ float silu_f(float x) { return x / (1.f + __expf(-x)); }

// ---------------------------------------------------------------------------
// Generic tiled fp32 GEMM (edge ops only): C[M,N] = A[M,K] @ W[K,N]
// EPI: 0 none, 1 +bias
// ---------------------------------------------------------------------------
template<int EPI>
__global__ __launch_bounds__(256) void gemm_f32(
    const float* __restrict__ A, int lda,
    const float* __restrict__ W, int ldw,
    const float* __restrict__ bias,
    float* __restrict__ C, int ldc,
    int M, int N, int K)
{
  __shared__ float As[BKt][BMt];   // [k][m]
  __shared__ float Ws[BKt][BNt];   // [k][n]
  const int tid = threadIdx.x;
  const int tx = tid & 15, ty = tid >> 4;
  const int m0 = blockIdx.y * BMt, n0 = blockIdx.x * BNt;
  const int am = tid >> 2, ak4 = (tid & 3) << 2;
  const int wk = tid >> 4, wn4 = (tid & 15) << 2;

  float acc[4][4] = {};

  for (int k0 = 0; k0 < K; k0 += BKt) {
    float4 va = make_float4(0.f, 0.f, 0.f, 0.f);
    {
      int m = m0 + am;
      if (m < M) {
        if (k0 + ak4 + 3 < K) {
          va = *reinterpret_cast<const float4*>(&A[(size_t)m * lda + k0 + ak4]);
        } else {
          float t[4];
          #pragma unroll
          for (int j = 0; j < 4; ++j)
            t[j] = (k0 + ak4 + j < K) ? A[(size_t)m * lda + k0 + ak4 + j] : 0.f;
          va = make_float4(t[0], t[1], t[2], t[3]);
        }
      }
    }
    As[ak4 + 0][am] = va.x;
    As[ak4 + 1][am] = va.y;
    As[ak4 + 2][am] = va.z;
    As[ak4 + 3][am] = va.w;

    float4 vw = make_float4(0.f, 0.f, 0.f, 0.f);
    {
      int kw = k0 + wk;
      if (kw < K) {
        if (n0 + wn4 + 3 < N) {
          vw = *reinterpret_cast<const float4*>(&W[(size_t)kw * ldw + n0 + wn4]);
        } else {
          float t[4];
          #pragma unroll
          for (int j = 0; j < 4; ++j)
            t[j] = (n0 + wn4 + j < N) ? W[(size_t)kw * ldw + n0 + wn4 + j] : 0.f;
          vw = make_float4(t[0], t[1], t[2], t[3]);
        }
      }
    }
    *reinterpret_cast<float4*>(&Ws[wk][wn4]) = vw;

    __syncthreads();
    #pragma unroll
    for (int kk = 0; kk < BKt; ++kk) {
      const float4 a4 = *reinterpret_cast<const float4*>(&As[kk][ty << 2]);
      const float4 w4 = *reinterpret_cast<const float4*>(&Ws[kk][tx << 2]);
      float av[4] = {a4.x, a4.y, a4.z, a4.w};
      float wv[4] = {w4.x, w4.y, w4.z, w4.w};
      #pragma unroll
      for (int i = 0; i < 4; ++i)
        #pragma unroll
        for (int j = 0; j < 4; ++j)
          acc[i][j] += av[i] * wv[j];
    }
    __syncthreads();
  }

  #pragma unroll
  for (int i = 0; i < 4; ++i) {
    int row = m0 + (ty << 2) + i;
    if (row >= M) continue;
    #pragma unroll
    for (int j = 0; j < 4; ++j) {
      int col = n0 + (tx << 2) + j;
      if (col >= N) continue;
      float v = acc[i][j];
      if (EPI == 1) v += bias[col];
      C[(size_t)row * ldc + col] = v;
    }
  }
}

// ---------------------------------------------------------------------------
// Split-K x-proj: part[s][M][56] = xs[:, s*96:(s+1)*96] @ xp[s*96:(s+1)*96, :]
// ---------------------------------------------------------------------------
__global__ __launch_bounds__(256) void xproj_splitk_kernel(
    const float* __restrict__ A,   // [M][768] = xs
    const float* __restrict__ W,   // [768][56] layer slice
    float* __restrict__ part)      // [XP_SPLIT][M][56]
{
  __shared__ float As[BKt][BMt];
  __shared__ float Ws[BKt][BNt];
  const int tid = threadIdx.x;
  const int tx = tid & 15, ty = tid >> 4;
  const int split = blockIdx.x;
  const int m0 = blockIdx.y * BMt;
  const int am = tid >> 2, ak4 = (tid & 3) << 2;
  const int wk = tid >> 4, wn4 = (tid & 15) << 2;
  const int kbase = split * XP_KC;

  float acc[4][4] = {};

  for (int k0 = 0; k0 < XP_KC; k0 += BKt) {
    float4 va = *reinterpret_cast<const float4*>(
        &A[(size_t)(m0 + am) * D_INNER + kbase + k0 + ak4]);
    As[ak4 + 0][am] = va.x;
    As[ak4 + 1][am] = va.y;
    As[ak4 + 2][am] = va.z;
    As[ak4 + 3][am] = va.w;

    float4 vw = make_float4(0.f, 0.f, 0.f, 0.f);
    if (wn4 < XP_N)
      vw = *reinterpret_cast<const float4*>(&W[(size_t)(kbase + k0 + wk) * XP_N + wn4]);
    *reinterpret_cast<float4*>(&Ws[wk][wn4]) = vw;

    __syncthreads();
    #pragma unroll
    for (int kk = 0; kk < BKt; ++kk) {
      const float4 a4 = *reinterpret_cast<const float4*>(&As[kk][ty << 2]);
      const float4 w4 = *reinterpret_cast<const float4*>(&Ws[kk][tx << 2]);
      float av[4] = {a4.x, a4.y, a4.z, a4.w};
      float wv[4] = {w4.x, w4.y, w4.z, w4.w};
      #pragma unroll
      for (int i = 0; i < 4; ++i)
        #pragma unroll
        for (int j = 0; j < 4; ++j)
          acc[i][j] += av[i] * wv[j];
    }
    __syncthreads();
  }

  #pragma unroll
  for (int i = 0; i < 4; ++i) {
    int row = m0 + (ty << 2) + i;
    #pragma unroll
    for (int j = 0; j < 4; ++j) {
      int col = (tx << 2) + j;
      if (col < XP_N)
        part[((size_t)split * MTOK + row) * XP_N + col] = acc[i][j];
    }
  }
}

__global__ __launch_bounds__(256) void xproj_reduce_kernel(
    const float* __restrict__ part, float* __restrict__ xdbl)
{
  int idx = blockIdx.x * 256 + threadIdx.x;
  if (idx >= MTOK * XP_N) return;
  float s = 0.f;
  #pragma unroll
  for (int p = 0; p < XP_SPLIT; ++p)
    s += part[(size_t)p * MTOK * XP_N + idx];
  xdbl[idx] = s;
}

// ---------------------------------------------------------------------------
// bf16 MFMA GEMM: C_f32[M,N] = A_bf16[M,K] @ WT_bf16[N,K]
// EPI: 0 none, 3 +resid. M,N,K multiples of 64.
// ---------------------------------------------------------------------------
template<int EPI>
__global__ __launch_bounds__(256) void gemm_bf16(
    const __hip_bfloat16* __restrict__ A,   // [M][K]
    const __hip_bfloat16* __restrict__ WT,  // [N][K]
    const float* __restrict__ resid,
    float* __restrict__ C, int ldc,
    int M, int N, int K)
{
  __shared__ __align__(16) __hip_bfloat16 Asl[64][72];
  __shared__ __align__(16) __hip_bfloat16 Bsl[64][72];
  const int tid = threadIdx.x;
  const int wave = tid >> 6, lane = tid & 63;
  const int m0 = blockIdx.y * 64, n0 = blockIdx.x * 64;
  const int lrow = tid >> 2;
  const int lk   = (tid & 3) << 4;
  const int g16 = lane >> 4;
  const int l16 = lane & 15;

  f32x4 acc[4] = {};

  for (int k0 = 0; k0 < K; k0 += 64) {
    const uint4* ga = reinterpret_cast<const uint4*>(&A[(size_t)(m0 + lrow) * K + k0 + lk]);
    uint4* la = reinterpret_cast<uint4*>(&Asl[lrow][lk]);
    la[0] = ga[0]; la[1] = ga[1];
    const uint4* gb = reinterpret_cast<const uint4*>(&WT[(size_t)(n0 + lrow) * K + k0 + lk]);
    uint4* lb = reinterpret_cast<uint4*>(&Bsl[lrow][lk]);
    lb[0] = gb[0]; lb[1] = gb[1];
    __syncthreads();
    #pragma unroll
    for (int kk = 0; kk < 64; kk += 32) {
      bf16x8 a = *reinterpret_cast<const bf16x8*>(&Asl[wave * 16 + l16][kk + g16 * 8]);
      #pragma unroll
      for (int f = 0; f < 4; ++f) {
        bf16x8 b = *reinterpret_cast<const bf16x8*>(&Bsl[f * 16 + l16][kk + g16 * 8]);
        acc[f] = __builtin_amdgcn_mfma_f32_16x16x32_bf16(a, b, acc[f], 0, 0, 0);
      }
    }
    __syncthreads();
  }

  #pragma unroll
  for (int f = 0; f < 4; ++f) {
    #pragma unroll
    for (int r = 0; r < 4; ++r) {
      int row = m0 + wave * 16 + g16 * 4 + r;
      int col = n0 + f * 16 + l16;
      float v = acc[f][r];
      if (EPI == 3) v += resid[(size_t)row * ldc + col];
      C[(size_t)row * ldc + col] = v;
    }
  }
}

// ---------------------------------------------------------------------------
// Weight convert + transpose: src f32 [L][K][N] -> dst bf16 [L][N][K]
// ---------------------------------------------------------------------------
__global__ __launch_bounds__(256) void wconv_t_kernel(
    const float* __restrict__ src, __hip_bfloat16* __restrict__ dst,
    int K, int N)
{
  __shared__ float tile[32][33];
  int l = blockIdx.z;
  int kb = blockIdx.y * 32, nb = blockIdx.x * 32;
  int tn = threadIdx.x & 31, tk = threadIdx.x >> 5;  // 32 x 8
  const float* s = src + (size_t)l * K * N;
  __hip_bfloat16* dd = dst + (size_t)l * N * K;
  #pragma unroll
  for (int i = 0; i < 4; ++i) {
    int k = kb + tk + i * 8, n = nb + tn;
    tile[tk + i * 8][tn] = (k < K && n < N) ? s[(size_t)k * N + n] : 0.f;
  }
  __syncthreads();
  #pragma unroll
  for (int i = 0; i < 4; ++i) {
    int n = nb + tk + i * 8, k = kb + tn;
    if (n < N && k < K) dd[(size_t)n * K + k] = __float2bfloat16(tile[tn][tk + i * 8]);
  }
}

// ---------------------------------------------------------------------------
// RMSNorm: one wave per row; writes fp32 and bf16 copies
// ---------------------------------------------------------------------------
__global__ __launch_bounds__(256) void rmsnorm_kernel(
    const float* __restrict__ x, const float* __restrict__ w,
    float* __restrict__ out, __hip_bfloat16* __restrict__ outb, int M, int N)
{
  int gw = (blockIdx.x * blockDim.x + threadIdx.x) >> 6;
  int lane = threadIdx.x & 63;
  if (gw >= M) return;
  const float* row = x + (size_t)gw * N;
  float ss = 0.f;
  for (int j = lane; j < N; j += 64) { float v = row[j]; ss += v * v; }
  #pragma unroll
  for (int off = 32; off; off >>= 1) ss += __shfl_xor(ss, off, 64);
  float scale = rsqrtf(ss / (float)N + 1e-5f);
  float* orow = out + (size_t)gw * N;
  __hip_bfloat16* brow = outb + (size_t)gw * N;
  for (int j = lane; j < N; j += 64) {
    float v = row[j] * scale * w[j];
    orow[j] = v;
    brow[j] = __float2bfloat16(v);
  }
}

// ---------------------------------------------------------------------------
// Depthwise causal conv (k=4) + bias + SiLU.
// ---------------------------------------------------------------------------
__global__ __launch_bounds__(256) void conv_silu_kernel(
    const float* __restrict__ xr, const float* __restrict__ cw,
    const float* __restrict__ cb, float* __restrict__ xs)
{
  int idx = blockIdx.x * 256 + threadIdx.x;
  if (idx >= MTOK * D_INNER) return;
  int m = idx / D_INNER;
  int d = idx - m * D_INNER;
  int b = m >> 9, l = m & 511;
  float acc = 0.f;
  #pragma unroll
  for (int k = 0; k < D_CONV; ++k) {
    int t = l - (D_CONV - 1) + k;
    if (t >= 0) acc += xr[((size_t)(b * LL + t)) * (2 * D_INNER) + d] * cw[d * D_CONV + k];
  }
  acc += cb[d];
  xs[idx] = silu_f(acc);
}

// ---------------------------------------------------------------------------
// Chunked parallel selective scan v3: 512 threads = 32 chunks x 16 states,
// T=16 steps/chunk. Phase 1 stashes a[t], dBu[t] in registers so phase 3 is
// just h = a*h + dbu (no exp/B-load/LDS-read recompute). Reduce over n via
// 2 shfl_xor (16->4) + LDS partial + final 1-l-per-thread pass fusing
// D-term + silu(res) gate + bf16 write. dt-proj stays fused in staging.
// XCD-swizzled block decode unchanged.
// ---------------------------------------------------------------------------
#define SC3_T  16
#define SC3_NC 32
__global__ __launch_bounds__(512) void scan_kernel3(
    const float* __restrict__ xs,     // M x 768 (u)
    const float* __restrict__ xdbl,   // M x 56 (dt|B|C)
    const float* __restrict__ A_log,  // 768 x 16 (layer slice)
    const float* __restrict__ Dp,     // 768
    const float* __restrict__ dtw,    // [24][768] layer slice
    const float* __restrict__ dtb,    // [768] layer slice
    const float* __restrict__ xr,     // M x 1536 (res = cols 768..)
    __hip_bfloat16* __restrict__ yg)  // M x 768 bf16
{
  __shared__ float sdelta[LL];
  __shared__ float su[LL];
  __shared__ float sdw[DT_RANK];
  __shared__ float sP[SC3_NC][D_STATE];
  __shared__ float sS[SC3_NC][D_STATE];
  __shared__ float sH0[SC3_NC][D_STATE];
  __shared__ float sY[LL][4];

  const int id = blockIdx.x;
  const int r  = id / 96;        // 0..31
  const int G  = id % 96;        // 0..95  (id%8 == G%8 -> line-sharing d's on one XCD)
  const int b  = G / 24;         // 0..3
  const int d  = (G % 24) * 32 + r;

  const int tid = threadIdx.x;   // 0..511
  const int n = tid & 15;
  const int c = tid >> 4;        // 0..31

  if (tid < DT_RANK) sdw[tid] = dtw[tid * D_INNER + d];
  __syncthreads();

  // staging: one l per thread; dt-proj dot as 6x float4
  {
    const int l = tid;
    const size_t m = (size_t)(b * LL + l);
    float acc = dtb[d];
    const float* xrow = &xdbl[m * 56];
    #pragma unroll
    for (int k4 = 0; k4 < DT_RANK; k4 += 4) {
      float4 xv = *reinterpret_cast<const float4*>(&xrow[k4]);
      acc += xv.x * sdw[k4] + xv.y * sdw[k4 + 1] + xv.z * sdw[k4 + 2] + xv.w * sdw[k4 + 3];
    }
    sdelta[l] = (acc > 20.f) ? acc : log1pf(__expf(acc));
    su[l]     = xs[m * D_INNER + d];
  }

  const float Aval = -__expf(A_log[d * D_STATE + n]);
  __syncthreads();

  // Phase 1: per-chunk affine composition, stash a/dbu
  float a_s[SC3_T], dbu_s[SC3_T];
  const int l0 = c * SC3_T;
  {
    float P = 1.f, S = 0.f;
    #pragma unroll
    for (int t = 0; t < SC3_T; ++t) {
      int l = l0 + t;
      size_t m = (size_t)(b * LL + l);
      float dv = sdelta[l];
      float uv = su[l];
      float Bv = xdbl[m * 56 + DT_RANK + n];
      float a = __expf(dv * Aval);
      float dbu = (dv * Bv) * uv;
      P *= a;
      S = a * S + dbu;
      a_s[t] = a;
      dbu_s[t] = dbu;
    }
    sP[c][n] = P;
    sS[c][n] = S;
  }
  __syncthreads();

  // Phase 2: serial compose across 32 chunks (16 threads)
  if (tid < D_STATE) {
    float hh = 0.f;
    #pragma unroll
    for (int cc = 0; cc < SC3_NC; ++cc) {
      sH0[cc][tid] = hh;
      hh = sP[cc][tid] * hh + sS[cc][tid];
    }
  }
  __syncthreads();

  // Phase 3: replay from stashed a/dbu; 2-shfl partial reduce to LDS
  {
    float h = sH0[c][n];
    #pragma unroll
    for (int t = 0; t < SC3_T; ++t) {
      int l = l0 + t;
      size_t m = (size_t)(b * LL + l);
      float Cv = xdbl[m * 56 + DT_RANK + D_STATE + n];
      h = a_s[t] * h + dbu_s[t];
      float contrib = h * Cv;
      contrib += __shfl_xor(contrib, 1, 64);
      contrib += __shfl_xor(contrib, 2, 64);
      if ((n & 3) == 0) sY[l][n >> 2] = contrib;
    }
  }
  __syncthreads();

  // Final: one l per thread — sum 4 partials, D-term, gate, bf16 write
  {
    const int l = tid;
    const size_t m = (size_t)(b * LL + l);
    float4 p4 = *reinterpret_cast<const float4*>(&sY[l][0]);
    float y = (p4.x + p4.y) + (p4.z + p4.w) + su[l] * Dp[d];
    float rres = xr[m * (2 * D_INNER) + D_INNER + d];
    yg[m * D_INNER + d] = __float2bfloat16(y * silu_f(rres));
  }
}

// ---------------------------------------------------------------------------
// Attention: out[b,q,:] = softmax_k(h[b,q,:]·enc[b,k,:]) @ enc[b]
// ---------------------------------------------------------------------------
#define TQ 8
__global__ __launch_bounds__(512) void attn_kernel(
    const float* __restrict__ h, const float* __restrict__ enc,
    float* __restrict__ out)
{
  __shared__ float hrow[TQ][D_MODEL];
  __shared__ float p[TQ][LL];
  int blk = blockIdx.x;
  int b = blk / (LL / TQ);
  int q0 = (blk % (LL / TQ)) * TQ;
  int tid = threadIdx.x;

  for (int i = tid; i < TQ * D_MODEL; i += 512) {
    int qi = i / D_MODEL, j = i - qi * D_MODEL;
    hrow[qi][j] = h[((size_t)b * LL + q0 + qi) * D_MODEL + j];
  }
  __syncthreads();

  {
    int k = tid;
    const float* er = enc + ((size_t)b * LL + k) * D_MODEL;
    float acc[TQ] = {};
    for (int j = 0; j < D_MODEL; ++j) {
      float e = er[j];
      #pragma unroll
      for (int qi = 0; qi < TQ; ++qi) acc[qi] += hrow[qi][j] * e;
    }
    #pragma unroll
    for (int qi = 0; qi < TQ; ++qi) p[qi][k] = acc[qi];
  }
  __syncthreads();

  {
    int w = tid >> 6, lane = tid & 63;
    float mx = -1e30f;
    for (int k = lane; k < LL; k += 64) mx = fmaxf(mx, p[w][k]);
    #pragma unroll
    for (int off = 32; off; off >>= 1) mx = fmaxf(mx, __shfl_xor(mx, off, 64));
    float sum = 0.f;
    for (int k = lane; k < LL; k += 64) { float e = __expf(p[w][k] - mx); p[w][k] = e; sum += e; }
    #pragma unroll
    for (int off = 32; off; off >>= 1) sum += __shfl_xor(sum, off, 64);
    float inv = 1.f / sum;
    for (int k = lane; k < LL; k += 64) p[w][k] *= inv;
  }
  __syncthreads();

  if (tid < D_MODEL) {
    int d = tid;
    float acc[TQ] = {};
    for (int k = 0; k < LL; ++k) {
      float e = enc[((size_t)b * LL + k) * D_MODEL + d];
      #pragma unroll
      for (int qi = 0; qi < TQ; ++qi) acc[qi] += p[qi][k] * e;
    }
    #pragma unroll
    for (int qi = 0; qi < TQ; ++qi)
      out[((size_t)b * LL + q0 + qi) * D_MODEL + d] = acc[qi];
  }
}

// ---------------------------------------------------------------------------
extern "C" void kernel_launch(void* const* d_in, const int* in_sizes, int n_in,
                              void* d_out, int out_size, void* d_ws, size_t ws_size,
                              hipStream_t stream) {
  const float* x        = (const float*)d_in[0];
  const float* enc      = (const float*)d_in[1];
  const float* w_in     = (const float*)d_in[2];
  const float* b_in     = (const float*)d_in[3];
  const float* ln_w     = (const float*)d_in[4];
  const float* inproj_w = (const float*)d_in[5];
  const float* conv_w   = (const float*)d_in[6];
  const float* conv_b   = (const float*)d_in[7];
  const float* xproj_w  = (const float*)d_in[8];
  const float* dtproj_w = (const float*)d_in[9];
  const float* dtproj_b = (const float*)d_in[10];
  const float* A_log    = (const float*)d_in[11];
  const float* Dvec     = (const float*)d_in[12];
  const float* outproj_w= (const float*)d_in[13];
  const float* normf_w  = (const float*)d_in[14];
  const float* w_out    = (const float*)d_in[15];

  float* ws = (float*)d_ws;
  float* h     = ws; ws += MTOK * D_MODEL;
  float* hn    = ws; ws += MTOK * D_MODEL;
  float* xr    = ws; ws += MTOK * 2 * D_INNER;
  float* xs    = ws; ws += MTOK * D_INNER;
  float* xdbl  = ws; ws += MTOK * XP_N;
  float* xpart = ws; ws += XP_SPLIT * MTOK * XP_N;
  float* h2    = ws; ws += MTOK * D_MODEL;
  __hip_bfloat16* hn_bf = (__hip_bfloat16*)ws; ws += MTOK * D_MODEL / 2;
  __hip_bfloat16* yg_bf = (__hip_bfloat16*)ws; ws += MTOK * D_INNER / 2;
  __hip_bfloat16* WinT  = (__hip_bfloat16*)ws; ws += N_LAYER * D_MODEL * 2 * D_INNER / 2;
  __hip_bfloat16* WoutT = (__hip_bfloat16*)ws; ws += N_LAYER * D_INNER * D_MODEL / 2;

  dim3 blk256(256), blk512(512);

  // Prologue: convert+transpose big weights to bf16 [N][K]
  wconv_t_kernel<<<dim3(2 * D_INNER / 32, D_MODEL / 32, N_LAYER), blk256, 0, stream>>>(
      inproj_w, WinT, D_MODEL, 2 * D_INNER);
  wconv_t_kernel<<<dim3(D_MODEL / 32, D_INNER / 32, N_LAYER), blk256, 0, stream>>>(
      outproj_w, WoutT, D_INNER, D_MODEL);

  // input projection: h = x @ w_in + b_in  (fp32)
  gemm_f32<1><<<dim3(D_MODEL / BNt, MTOK / BMt), blk256, 0, stream>>>(
      x, N_MELS, w_in, D_MODEL, b_in, h, D_MODEL, MTOK, D_MODEL, N_MELS);

  auto mamba = [&](float* hcur, int i) {
    rmsnorm_kernel<<<MTOK * 64 / 256, blk256, 0, stream>>>(
        hcur, ln_w + (size_t)i * D_MODEL, hn, hn_bf, MTOK, D_MODEL);
    // in-proj (bf16 MFMA): xr = hn @ inproj_w
    gemm_bf16<0><<<dim3(2 * D_INNER / 64, MTOK / 64), blk256, 0, stream>>>(
        hn_bf, WinT + (size_t)i * D_MODEL * 2 * D_INNER, nullptr,
        xr, 2 * D_INNER, MTOK, 2 * D_INNER, D_MODEL);
    conv_silu_kernel<<<MTOK * D_INNER / 256, blk256, 0, stream>>>(
        xr, conv_w + (size_t)i * D_INNER * D_CONV, conv_b + (size_t)i * D_INNER, xs);
    // x-proj split-K + reduce
    xproj_splitk_kernel<<<dim3(XP_SPLIT, MTOK / BMt), blk256, 0, stream>>>(
        xs, xproj_w + (size_t)i * D_INNER * XP_N, xpart);
    xproj_reduce_kernel<<<(MTOK * XP_N + 255) / 256, blk256, 0, stream>>>(xpart, xdbl);
    // scan v3 (dt-proj fused)
    scan_kernel3<<<BB * D_INNER, blk512, 0, stream>>>(
        xs, xdbl, A_log + (size_t)i * D_INNER * D_STATE, Dvec + (size_t)i * D_INNER,
        dtproj_w + (size_t)i * DT_RANK * D_INNER, dtproj_b + (size_t)i * D_INNER,
        xr, yg_bf);
    // out-proj (bf16 MFMA) + residual: hcur += yg @ outproj_w
    gemm_bf16<3><<<dim3(D_MODEL / 64, MTOK / 64), blk256, 0, stream>>>(
        yg_bf, WoutT + (size_t)i * D_INNER * D_MODEL, hcur,
        hcur, D_MODEL, MTOK, D_MODEL, D_INNER);
  };

  for (int i = 0; i < N_LAYER / 2; ++i) mamba(h, i);

  attn_kernel<<<MTOK / TQ, blk512, 0, stream>>>(h, enc, h2);

  for (int i = N_LAYER / 2; i < N_LAYER; ++i) mamba(h2, i);

  rmsnorm_kernel<<<MTOK * 64 / 256, blk256, 0, stream>>>(h2, normf_w, hn, hn_bf, MTOK, D_MODEL);
  gemm_f32<0><<<dim3((N_MELS + BNt - 1) / BNt, MTOK / BMt), blk256, 0, stream>>>(
      hn, D_MODEL, w_out, N_MELS, nullptr, (float*)d_out, N_MELS, MTOK, N_MELS, D_MODEL);
}

// Round 8
// 925.538 us; speedup vs baseline: 4.9770x; 1.0707x over previous
//
#include <hip/hip_runtime.h>
#include <hip/hip_bf16.h>
#include <math.h>

// Problem dims (fixed by reference)
#define D_MODEL 384
#define N_LAYER 8
#define N_MELS  80
#define D_STATE 16
#define D_CONV  4
#define D_INNER 768
#define DT_RANK 24
#define BB      4
#define LL      512
#define MTOK    (BB*LL)   // 2048

#define BMt 64
#define BNt 64
#define BKt 16

#define XP_N   56
#define XPS    12           // split-K splits for x-proj
#define XPKC   64           // K per split

typedef __attribute__((ext_vector_type(8))) short bf16x8;
typedef __attribute__((ext_vector_type(4))) short bf16x4;
typedef __attribute__((ext_vector_type(4))) float f32x4;

__device__ __forceinline__ float silu_f(float x) { return x / (1.f + __expf(-x)); }
__device__ __forceinline__ short bf_raw(float x) {
  __hip_bfloat16 h = __float2bfloat16(x);
  return *reinterpret_cast<short*>(&h);
}

// ---------------------------------------------------------------------------
// Generic tiled fp32 GEMM (edge ops only): C[M,N] = A[M,K] @ W[K,N]
// EPI: 0 none, 1 +bias
// ---------------------------------------------------------------------------
template<int EPI>
__global__ __launch_bounds__(256) void gemm_f32(
    const float* __restrict__ A, int lda,
    const float* __restrict__ W, int ldw,
    const float* __restrict__ bias,
    float* __restrict__ C, int ldc,
    int M, int N, int K)
{
  __shared__ float As[BKt][BMt];
  __shared__ float Ws[BKt][BNt];
  const int tid = threadIdx.x;
  const int tx = tid & 15, ty = tid >> 4;
  const int m0 = blockIdx.y * BMt, n0 = blockIdx.x * BNt;
  const int am = tid >> 2, ak4 = (tid & 3) << 2;
  const int wk = tid >> 4, wn4 = (tid & 15) << 2;

  float acc[4][4] = {};

  for (int k0 = 0; k0 < K; k0 += BKt) {
    float4 va = make_float4(0.f, 0.f, 0.f, 0.f);
    {
      int m = m0 + am;
      if (m < M) {
        if (k0 + ak4 + 3 < K) {
          va = *reinterpret_cast<const float4*>(&A[(size_t)m * lda + k0 + ak4]);
        } else {
          float t[4];
          #pragma unroll
          for (int j = 0; j < 4; ++j)
            t[j] = (k0 + ak4 + j < K) ? A[(size_t)m * lda + k0 + ak4 + j] : 0.f;
          va = make_float4(t[0], t[1], t[2], t[3]);
        }
      }
    }
    As[ak4 + 0][am] = va.x;
    As[ak4 + 1][am] = va.y;
    As[ak4 + 2][am] = va.z;
    As[ak4 + 3][am] = va.w;

    float4 vw = make_float4(0.f, 0.f, 0.f, 0.f);
    {
      int kw = k0 + wk;
      if (kw < K) {
        if (n0 + wn4 + 3 < N) {
          vw = *reinterpret_cast<const float4*>(&W[(size_t)kw * ldw + n0 + wn4]);
        } else {
          float t[4];
          #pragma unroll
          for (int j = 0; j < 4; ++j)
            t[j] = (n0 + wn4 + j < N) ? W[(size_t)kw * ldw + n0 + wn4 + j] : 0.f;
          vw = make_float4(t[0], t[1], t[2], t[3]);
        }
      }
    }
    *reinterpret_cast<float4*>(&Ws[wk][wn4]) = vw;

    __syncthreads();
    #pragma unroll
    for (int kk = 0; kk < BKt; ++kk) {
      const float4 a4 = *reinterpret_cast<const float4*>(&As[kk][ty << 2]);
      const float4 w4 = *reinterpret_cast<const float4*>(&Ws[kk][tx << 2]);
      float av[4] = {a4.x, a4.y, a4.z, a4.w};
      float wv[4] = {w4.x, w4.y, w4.z, w4.w};
      #pragma unroll
      for (int i = 0; i < 4; ++i)
        #pragma unroll
        for (int j = 0; j < 4; ++j)
          acc[i][j] += av[i] * wv[j];
    }
    __syncthreads();
  }

  #pragma unroll
  for (int i = 0; i < 4; ++i) {
    int row = m0 + (ty << 2) + i;
    if (row >= M) continue;
    #pragma unroll
    for (int j = 0; j < 4; ++j) {
      int col = n0 + (tx << 2) + j;
      if (col >= N) continue;
      float v = acc[i][j];
      if (EPI == 1) v += bias[col];
      C[(size_t)row * ldc + col] = v;
    }
  }
}

// ---------------------------------------------------------------------------
// bf16 MFMA GEMM: C_f32[M,N] = A_bf16[M,K] @ WT_bf16[N,K]
// EPI: 0 none, 3 +resid. M,N,K multiples of 64.
// ---------------------------------------------------------------------------
template<int EPI>
__global__ __launch_bounds__(256) void gemm_bf16(
    const __hip_bfloat16* __restrict__ A,   // [M][K]
    const __hip_bfloat16* __restrict__ WT,  // [N][K]
    const float* __restrict__ resid,
    float* __restrict__ C, int ldc,
    int M, int N, int K)
{
  __shared__ __align__(16) __hip_bfloat16 Asl[64][72];
  __shared__ __align__(16) __hip_bfloat16 Bsl[64][72];
  const int tid = threadIdx.x;
  const int wave = tid >> 6, lane = tid & 63;
  const int m0 = blockIdx.y * 64, n0 = blockIdx.x * 64;
  const int lrow = tid >> 2;
  const int lk   = (tid & 3) << 4;
  const int g16 = lane >> 4;
  const int l16 = lane & 15;

  f32x4 acc[4] = {};

  for (int k0 = 0; k0 < K; k0 += 64) {
    const uint4* ga = reinterpret_cast<const uint4*>(&A[(size_t)(m0 + lrow) * K + k0 + lk]);
    uint4* la = reinterpret_cast<uint4*>(&Asl[lrow][lk]);
    la[0] = ga[0]; la[1] = ga[1];
    const uint4* gb = reinterpret_cast<const uint4*>(&WT[(size_t)(n0 + lrow) * K + k0 + lk]);
    uint4* lb = reinterpret_cast<uint4*>(&Bsl[lrow][lk]);
    lb[0] = gb[0]; lb[1] = gb[1];
    __syncthreads();
    #pragma unroll
    for (int kk = 0; kk < 64; kk += 32) {
      bf16x8 a = *reinterpret_cast<const bf16x8*>(&Asl[wave * 16 + l16][kk + g16 * 8]);
      #pragma unroll
      for (int f = 0; f < 4; ++f) {
        bf16x8 b = *reinterpret_cast<const bf16x8*>(&Bsl[f * 16 + l16][kk + g16 * 8]);
        acc[f] = __builtin_amdgcn_mfma_f32_16x16x32_bf16(a, b, acc[f], 0, 0, 0);
      }
    }
    __syncthreads();
  }

  #pragma unroll
  for (int f = 0; f < 4; ++f) {
    #pragma unroll
    for (int r = 0; r < 4; ++r) {
      int row = m0 + wave * 16 + g16 * 4 + r;
      int col = n0 + f * 16 + l16;
      float v = acc[f][r];
      if (EPI == 3) v += resid[(size_t)row * ldc + col];
      C[(size_t)row * ldc + col] = v;
    }
  }
}

// ---------------------------------------------------------------------------
// Batched bf16 MFMA GEMM (attention): per-z strides. C = A @ WT^T, f32 out.
// ---------------------------------------------------------------------------
__global__ __launch_bounds__(256) void gemm_bf16_bat(
    const __hip_bfloat16* __restrict__ A, size_t sA,
    const __hip_bfloat16* __restrict__ WT, size_t sW,
    float* __restrict__ C, size_t sC,
    int M, int N, int K)
{
  A  += (size_t)blockIdx.z * sA;
  WT += (size_t)blockIdx.z * sW;
  C  += (size_t)blockIdx.z * sC;
  __shared__ __align__(16) __hip_bfloat16 Asl[64][72];
  __shared__ __align__(16) __hip_bfloat16 Bsl[64][72];
  const int tid = threadIdx.x;
  const int wave = tid >> 6, lane = tid & 63;
  const int m0 = blockIdx.y * 64, n0 = blockIdx.x * 64;
  const int lrow = tid >> 2;
  const int lk   = (tid & 3) << 4;
  const int g16 = lane >> 4;
  const int l16 = lane & 15;

  f32x4 acc[4] = {};

  for (int k0 = 0; k0 < K; k0 += 64) {
    const uint4* ga = reinterpret_cast<const uint4*>(&A[(size_t)(m0 + lrow) * K + k0 + lk]);
    uint4* la = reinterpret_cast<uint4*>(&Asl[lrow][lk]);
    la[0] = ga[0]; la[1] = ga[1];
    const uint4* gb = reinterpret_cast<const uint4*>(&WT[(size_t)(n0 + lrow) * K + k0 + lk]);
    uint4* lb = reinterpret_cast<uint4*>(&Bsl[lrow][lk]);
    lb[0] = gb[0]; lb[1] = gb[1];
    __syncthreads();
    #pragma unroll
    for (int kk = 0; kk < 64; kk += 32) {
      bf16x8 a = *reinterpret_cast<const bf16x8*>(&Asl[wave * 16 + l16][kk + g16 * 8]);
      #pragma unroll
      for (int f = 0; f < 4; ++f) {
        bf16x8 b = *reinterpret_cast<const bf16x8*>(&Bsl[f * 16 + l16][kk + g16 * 8]);
        acc[f] = __builtin_amdgcn_mfma_f32_16x16x32_bf16(a, b, acc[f], 0, 0, 0);
      }
    }
    __syncthreads();
  }

  #pragma unroll
  for (int f = 0; f < 4; ++f) {
    #pragma unroll
    for (int r = 0; r < 4; ++r) {
      int row = m0 + wave * 16 + g16 * 4 + r;
      int col = n0 + f * 16 + l16;
      C[(size_t)row * N + col] = acc[f][r];
    }
  }
}

// ---------------------------------------------------------------------------
// Split-K x-proj, bf16 MFMA: part[s][M][64] = xs[:, s*64:(s+1)*64] @ xpT rows
// xpT: [64 rows (56 valid + 8 pad)] x [768]; pad cols of part never read.
// ---------------------------------------------------------------------------
__global__ __launch_bounds__(256) void xproj_splitk_bf16(
    const __hip_bfloat16* __restrict__ A,    // [M][768] xs_bf
    const __hip_bfloat16* __restrict__ WT,   // [64][768] padded xprojT slice
    float* __restrict__ part)                // [XPS][M][64]
{
  __shared__ __align__(16) __hip_bfloat16 Asl[64][72];
  __shared__ __align__(16) __hip_bfloat16 Bsl[64][72];
  const int tid = threadIdx.x;
  const int wave = tid >> 6, lane = tid & 63;
  const int split = blockIdx.x;
  const int m0 = blockIdx.y * 64;
  const int kbase = split * XPKC;
  const int lrow = tid >> 2;
  const int lk   = (tid & 3) << 4;
  const int g16 = lane >> 4;
  const int l16 = lane & 15;

  f32x4 acc[4] = {};

  const uint4* ga = reinterpret_cast<const uint4*>(&A[(size_t)(m0 + lrow) * D_INNER + kbase + lk]);
  uint4* la = reinterpret_cast<uint4*>(&Asl[lrow][lk]);
  la[0] = ga[0]; la[1] = ga[1];
  const uint4* gb = reinterpret_cast<const uint4*>(&WT[(size_t)lrow * D_INNER + kbase + lk]);
  uint4* lb = reinterpret_cast<uint4*>(&Bsl[lrow][lk]);
  lb[0] = gb[0]; lb[1] = gb[1];
  __syncthreads();
  #pragma unroll
  for (int kk = 0; kk < 64; kk += 32) {
    bf16x8 a = *reinterpret_cast<const bf16x8*>(&Asl[wave * 16 + l16][kk + g16 * 8]);
    #pragma unroll
    for (int f = 0; f < 4; ++f) {
      bf16x8 b = *reinterpret_cast<const bf16x8*>(&Bsl[f * 16 + l16][kk + g16 * 8]);
      acc[f] = __builtin_amdgcn_mfma_f32_16x16x32_bf16(a, b, acc[f], 0, 0, 0);
    }
  }

  #pragma unroll
  for (int f = 0; f < 4; ++f) {
    #pragma unroll
    for (int r = 0; r < 4; ++r) {
      int row = m0 + wave * 16 + g16 * 4 + r;
      int col = f * 16 + l16;
      part[((size_t)split * MTOK + row) * 64 + col] = acc[f][r];
    }
  }
}

__global__ __launch_bounds__(256) void xproj_reduce_kernel(
    const float* __restrict__ part, float* __restrict__ xdbl)
{
  int idx = blockIdx.x * 256 + threadIdx.x;
  if (idx >= MTOK * XP_N) return;
  int m = idx / XP_N, col = idx - m * XP_N;
  float s = 0.f;
  #pragma unroll
  for (int p = 0; p < XPS; ++p)
    s += part[((size_t)p * MTOK + m) * 64 + col];
  xdbl[idx] = s;
}

// ---------------------------------------------------------------------------
// Weight convert + transpose: src f32 [L][K][N] -> dst bf16 [L][N][K]
// ldl = per-layer dst stride (elements) to allow row padding.
// ---------------------------------------------------------------------------
__global__ __launch_bounds__(256) void wconv_t_kernel(
    const float* __restrict__ src, __hip_bfloat16* __restrict__ dst,
    int K, int N, size_t ldl)
{
  __shared__ float tile[32][33];
  int l = blockIdx.z;
  int kb = blockIdx.y * 32, nb = blockIdx.x * 32;
  int tn = threadIdx.x & 31, tk = threadIdx.x >> 5;  // 32 x 8
  const float* s = src + (size_t)l * K * N;
  __hip_bfloat16* dd = dst + (size_t)l * ldl;
  #pragma unroll
  for (int i = 0; i < 4; ++i) {
    int k = kb + tk + i * 8, n = nb + tn;
    tile[tk + i * 8][tn] = (k < K && n < N) ? s[(size_t)k * N + n] : 0.f;
  }
  __syncthreads();
  #pragma unroll
  for (int i = 0; i < 4; ++i) {
    int n = nb + tk + i * 8, k = kb + tn;
    if (n < N && k < K) dd[(size_t)n * K + k] = __float2bfloat16(tile[tn][tk + i * 8]);
  }
}

// ---------------------------------------------------------------------------
// f32 -> bf16 elementwise convert (n multiple of 4)
// ---------------------------------------------------------------------------
__global__ __launch_bounds__(256) void f2b_kernel(
    const float* __restrict__ src, __hip_bfloat16* __restrict__ dst, int n)
{
  int i = (blockIdx.x * 256 + threadIdx.x) * 4;
  if (i >= n) return;
  float4 v = *reinterpret_cast<const float4*>(&src[i]);
  bf16x4 o;
  o[0] = bf_raw(v.x); o[1] = bf_raw(v.y); o[2] = bf_raw(v.z); o[3] = bf_raw(v.w);
  *reinterpret_cast<bf16x4*>(&dst[i]) = o;
}

// ---------------------------------------------------------------------------
// Row softmax: scores f32 [R][512] -> P bf16 [R][512]; one wave per row.
// ---------------------------------------------------------------------------
__global__ __launch_bounds__(256) void softmax_rows_kernel(
    const float* __restrict__ scores, __hip_bfloat16* __restrict__ P)
{
  int row = (blockIdx.x * 256 + threadIdx.x) >> 6;
  int lane = threadIdx.x & 63;
  if (row >= BB * LL) return;
  const float* s = scores + (size_t)row * LL + lane * 8;
  float4 v0 = *reinterpret_cast<const float4*>(s);
  float4 v1 = *reinterpret_cast<const float4*>(s + 4);
  float mx = fmaxf(fmaxf(fmaxf(v0.x, v0.y), fmaxf(v0.z, v0.w)),
                   fmaxf(fmaxf(v1.x, v1.y), fmaxf(v1.z, v1.w)));
  #pragma unroll
  for (int off = 32; off; off >>= 1) mx = fmaxf(mx, __shfl_xor(mx, off, 64));
  float e[8];
  e[0] = __expf(v0.x - mx); e[1] = __expf(v0.y - mx);
  e[2] = __expf(v0.z - mx); e[3] = __expf(v0.w - mx);
  e[4] = __expf(v1.x - mx); e[5] = __expf(v1.y - mx);
  e[6] = __expf(v1.z - mx); e[7] = __expf(v1.w - mx);
  float sum = ((e[0] + e[1]) + (e[2] + e[3])) + ((e[4] + e[5]) + (e[6] + e[7]));
  #pragma unroll
  for (int off = 32; off; off >>= 1) sum += __shfl_xor(sum, off, 64);
  float inv = 1.f / sum;
  bf16x8 o;
  #pragma unroll
  for (int j = 0; j < 8; ++j) o[j] = bf_raw(e[j] * inv);
  *reinterpret_cast<bf16x8*>(&P[(size_t)row * LL + lane * 8]) = o;
}

// ---------------------------------------------------------------------------
// RMSNorm: one wave per row; writes fp32 and bf16 copies
// ---------------------------------------------------------------------------
__global__ __launch_bounds__(256) void rmsnorm_kernel(
    const float* __restrict__ x, const float* __restrict__ w,
    float* __restrict__ out, __hip_bfloat16* __restrict__ outb, int M, int N)
{
  int gw = (blockIdx.x * blockDim.x + threadIdx.x) >> 6;
  int lane = threadIdx.x & 63;
  if (gw >= M) return;
  const float* row = x + (size_t)gw * N;
  float ss = 0.f;
  for (int j = lane; j < N; j += 64) { float v = row[j]; ss += v * v; }
  #pragma unroll
  for (int off = 32; off; off >>= 1) ss += __shfl_xor(ss, off, 64);
  float scale = rsqrtf(ss / (float)N + 1e-5f);
  float* orow = out + (size_t)gw * N;
  __hip_bfloat16* brow = outb + (size_t)gw * N;
  for (int j = lane; j < N; j += 64) {
    float v = row[j] * scale * w[j];
    orow[j] = v;
    brow[j] = __float2bfloat16(v);
  }
}

// ---------------------------------------------------------------------------
// Depthwise causal conv (k=4) + bias + SiLU -> bf16 xs
// ---------------------------------------------------------------------------
__global__ __launch_bounds__(256) void conv_silu_kernel(
    const float* __restrict__ xr, const float* __restrict__ cw,
    const float* __restrict__ cb, __hip_bfloat16* __restrict__ xsb)
{
  int idx = blockIdx.x * 256 + threadIdx.x;
  if (idx >= MTOK * D_INNER) return;
  int m = idx / D_INNER;
  int d = idx - m * D_INNER;
  int b = m >> 9, l = m & 511;
  float acc = 0.f;
  #pragma unroll
  for (int k = 0; k < D_CONV; ++k) {
    int t = l - (D_CONV - 1) + k;
    if (t >= 0) acc += xr[((size_t)(b * LL + t)) * (2 * D_INNER) + d] * cw[d * D_CONV + k];
  }
  acc += cb[d];
  xsb[idx] = __float2bfloat16(silu_f(acc));
}

// ---------------------------------------------------------------------------
// Chunked parallel selective scan v3 (u from bf16 xs).
// ---------------------------------------------------------------------------
#define SC3_T  16
#define SC3_NC 32
__global__ __launch_bounds__(512) void scan_kernel3(
    const __hip_bfloat16* __restrict__ xsb, // M x 768 (u, bf16)
    const float* __restrict__ xdbl,   // M x 56 (dt|B|C)
    const float* __restrict__ A_log,  // 768 x 16 (layer slice)
    const float* __restrict__ Dp,     // 768
    const float* __restrict__ dtw,    // [24][768] layer slice
    const float* __restrict__ dtb,    // [768] layer slice
    const float* __restrict__ xr,     // M x 1536 (res = cols 768..)
    __hip_bfloat16* __restrict__ yg)  // M x 768 bf16
{
  __shared__ float sdelta[LL];
  __shared__ float su[LL];
  __shared__ float sdw[DT_RANK];
  __shared__ float sP[SC3_NC][D_STATE];
  __shared__ float sS[SC3_NC][D_STATE];
  __shared__ float sH0[SC3_NC][D_STATE];
  __shared__ float sY[LL][4];

  const int id = blockIdx.x;
  const int r  = id / 96;        // 0..31
  const int G  = id % 96;        // 0..95  (id%8 == G%8 -> line-sharing d's on one XCD)
  const int b  = G / 24;         // 0..3
  const int d  = (G % 24) * 32 + r;

  const int tid = threadIdx.x;   // 0..511
  const int n = tid & 15;
  const int c = tid >> 4;        // 0..31

  if (tid < DT_RANK) sdw[tid] = dtw[tid * D_INNER + d];
  __syncthreads();

  {
    const int l = tid;
    const size_t m = (size_t)(b * LL + l);
    float acc = dtb[d];
    const float* xrow = &xdbl[m * 56];
    #pragma unroll
    for (int k4 = 0; k4 < DT_RANK; k4 += 4) {
      float4 xv = *reinterpret_cast<const float4*>(&xrow[k4]);
      acc += xv.x * sdw[k4] + xv.y * sdw[k4 + 1] + xv.z * sdw[k4 + 2] + xv.w * sdw[k4 + 3];
    }
    sdelta[l] = (acc > 20.f) ? acc : log1pf(__expf(acc));
    su[l]     = __bfloat162float(xsb[m * D_INNER + d]);
  }

  const float Aval = -__expf(A_log[d * D_STATE + n]);
  __syncthreads();

  // Phase 1: per-chunk affine composition, stash a/dbu
  float a_s[SC3_T], dbu_s[SC3_T];
  const int l0 = c * SC3_T;
  {
    float P = 1.f, S = 0.f;
    #pragma unroll
    for (int t = 0; t < SC3_T; ++t) {
      int l = l0 + t;
      size_t m = (size_t)(b * LL + l);
      float dv = sdelta[l];
      float uv = su[l];
      float Bv = xdbl[m * 56 + DT_RANK + n];
      float a = __expf(dv * Aval);
      float dbu = (dv * Bv) * uv;
      P *= a;
      S = a * S + dbu;
      a_s[t] = a;
      dbu_s[t] = dbu;
    }
    sP[c][n] = P;
    sS[c][n] = S;
  }
  __syncthreads();

  // Phase 2: serial compose across 32 chunks (16 threads)
  if (tid < D_STATE) {
    float hh = 0.f;
    #pragma unroll
    for (int cc = 0; cc < SC3_NC; ++cc) {
      sH0[cc][tid] = hh;
      hh = sP[cc][tid] * hh + sS[cc][tid];
    }
  }
  __syncthreads();

  // Phase 3: replay from stashed a/dbu; 2-shfl partial reduce to LDS
  {
    float h = sH0[c][n];
    #pragma unroll
    for (int t = 0; t < SC3_T; ++t) {
      int l = l0 + t;
      size_t m = (size_t)(b * LL + l);
      float Cv = xdbl[m * 56 + DT_RANK + D_STATE + n];
      h = a_s[t] * h + dbu_s[t];
      float contrib = h * Cv;
      contrib += __shfl_xor(contrib, 1, 64);
      contrib += __shfl_xor(contrib, 2, 64);
      if ((n & 3) == 0) sY[l][n >> 2] = contrib;
    }
  }
  __syncthreads();

  // Final: one l per thread — sum 4 partials, D-term, gate, bf16 write
  {
    const int l = tid;
    const size_t m = (size_t)(b * LL + l);
    float4 p4 = *reinterpret_cast<const float4*>(&sY[l][0]);
    float y = (p4.x + p4.y) + (p4.z + p4.w) + su[l] * Dp[d];
    float rres = xr[m * (2 * D_INNER) + D_INNER + d];
    yg[m * D_INNER + d] = __float2bfloat16(y * silu_f(rres));
  }
}

// ---------------------------------------------------------------------------
extern "C" void kernel_launch(void* const* d_in, const int* in_sizes, int n_in,
                              void* d_out, int out_size, void* d_ws, size_t ws_size,
                              hipStream_t stream) {
  const float* x        = (const float*)d_in[0];
  const float* enc      = (const float*)d_in[1];
  const float* w_in     = (const float*)d_in[2];
  const float* b_in     = (const float*)d_in[3];
  const float* ln_w     = (const float*)d_in[4];
  const float* inproj_w = (const float*)d_in[5];
  const float* conv_w   = (const float*)d_in[6];
  const float* conv_b   = (const float*)d_in[7];
  const float* xproj_w  = (const float*)d_in[8];
  const float* dtproj_w = (const float*)d_in[9];
  const float* dtproj_b = (const float*)d_in[10];
  const float* A_log    = (const float*)d_in[11];
  const float* Dvec     = (const float*)d_in[12];
  const float* outproj_w= (const float*)d_in[13];
  const float* normf_w  = (const float*)d_in[14];
  const float* w_out    = (const float*)d_in[15];

  float* ws = (float*)d_ws;
  float* h     = ws; ws += MTOK * D_MODEL;
  float* hn    = ws; ws += MTOK * D_MODEL;
  float* xr    = ws; ws += MTOK * 2 * D_INNER;
  float* xdbl  = ws; ws += MTOK * XP_N;
  float* xpart = ws; ws += XPS * MTOK * 64;
  float* h2    = ws; ws += MTOK * D_MODEL;
  float* scores= ws; ws += BB * LL * LL;
  __hip_bfloat16* hn_bf = (__hip_bfloat16*)ws; ws += MTOK * D_MODEL / 2;
  __hip_bfloat16* xs_bf = (__hip_bfloat16*)ws; ws += MTOK * D_INNER / 2;
  __hip_bfloat16* yg_bf = (__hip_bfloat16*)ws; ws += MTOK * D_INNER / 2;
  __hip_bfloat16* h_bf  = (__hip_bfloat16*)ws; ws += MTOK * D_MODEL / 2;
  __hip_bfloat16* P_bf  = (__hip_bfloat16*)ws; ws += BB * LL * LL / 2;
  __hip_bfloat16* enc_bf= (__hip_bfloat16*)ws; ws += BB * LL * D_MODEL / 2;
  __hip_bfloat16* encT  = (__hip_bfloat16*)ws; ws += BB * LL * D_MODEL / 2;
  __hip_bfloat16* WinT  = (__hip_bfloat16*)ws; ws += N_LAYER * D_MODEL * 2 * D_INNER / 2;
  __hip_bfloat16* WoutT = (__hip_bfloat16*)ws; ws += N_LAYER * D_INNER * D_MODEL / 2;
  __hip_bfloat16* XpT   = (__hip_bfloat16*)ws; ws += N_LAYER * 64 * D_INNER / 2;

  dim3 blk256(256), blk512(512);

  // Prologue: weight conversions
  wconv_t_kernel<<<dim3(2 * D_INNER / 32, D_MODEL / 32, N_LAYER), blk256, 0, stream>>>(
      inproj_w, WinT, D_MODEL, 2 * D_INNER, (size_t)2 * D_INNER * D_MODEL);
  wconv_t_kernel<<<dim3(D_MODEL / 32, D_INNER / 32, N_LAYER), blk256, 0, stream>>>(
      outproj_w, WoutT, D_INNER, D_MODEL, (size_t)D_MODEL * D_INNER);
  wconv_t_kernel<<<dim3((XP_N + 31) / 32, D_INNER / 32, N_LAYER), blk256, 0, stream>>>(
      xproj_w, XpT, D_INNER, XP_N, (size_t)64 * D_INNER);
  // enc conversions for attention
  f2b_kernel<<<(BB * LL * D_MODEL / 4 + 255) / 256, blk256, 0, stream>>>(
      enc, enc_bf, BB * LL * D_MODEL);
  wconv_t_kernel<<<dim3(D_MODEL / 32, LL / 32, BB), blk256, 0, stream>>>(
      enc, encT, LL, D_MODEL, (size_t)D_MODEL * LL);

  // input projection: h = x @ w_in + b_in  (fp32)
  gemm_f32<1><<<dim3(D_MODEL / BNt, MTOK / BMt), blk256, 0, stream>>>(
      x, N_MELS, w_in, D_MODEL, b_in, h, D_MODEL, MTOK, D_MODEL, N_MELS);

  auto mamba = [&](float* hcur, int i) {
    rmsnorm_kernel<<<MTOK * 64 / 256, blk256, 0, stream>>>(
        hcur, ln_w + (size_t)i * D_MODEL, hn, hn_bf, MTOK, D_MODEL);
    gemm_bf16<0><<<dim3(2 * D_INNER / 64, MTOK / 64), blk256, 0, stream>>>(
        hn_bf, WinT + (size_t)i * D_MODEL * 2 * D_INNER, nullptr,
        xr, 2 * D_INNER, MTOK, 2 * D_INNER, D_MODEL);
    conv_silu_kernel<<<MTOK * D_INNER / 256, blk256, 0, stream>>>(
        xr, conv_w + (size_t)i * D_INNER * D_CONV, conv_b + (size_t)i * D_INNER, xs_bf);
    xproj_splitk_bf16<<<dim3(XPS, MTOK / 64), blk256, 0, stream>>>(
        xs_bf, XpT + (size_t)i * 64 * D_INNER, xpart);
    xproj_reduce_kernel<<<(MTOK * XP_N + 255) / 256, blk256, 0, stream>>>(xpart, xdbl);
    scan_kernel3<<<BB * D_INNER, blk512, 0, stream>>>(
        xs_bf, xdbl, A_log + (size_t)i * D_INNER * D_STATE, Dvec + (size_t)i * D_INNER,
        dtproj_w + (size_t)i * DT_RANK * D_INNER, dtproj_b + (size_t)i * D_INNER,
        xr, yg_bf);
    gemm_bf16<3><<<dim3(D_MODEL / 64, MTOK / 64), blk256, 0, stream>>>(
        yg_bf, WoutT + (size_t)i * D_INNER * D_MODEL, hcur,
        hcur, D_MODEL, MTOK, D_MODEL, D_INNER);
  };

  for (int i = 0; i < N_LAYER / 2; ++i) mamba(h, i);

  // ---- attention via MFMA ----
  f2b_kernel<<<(MTOK * D_MODEL / 4 + 255) / 256, blk256, 0, stream>>>(
      h, h_bf, MTOK * D_MODEL);
  gemm_bf16_bat<<<dim3(LL / 64, LL / 64, BB), blk256, 0, stream>>>(
      h_bf, (size_t)LL * D_MODEL, enc_bf, (size_t)LL * D_MODEL,
      scores, (size_t)LL * LL, LL, LL, D_MODEL);
  softmax_rows_kernel<<<(BB * LL * 64) / 256, blk256, 0, stream>>>(scores, P_bf);
  gemm_bf16_bat<<<dim3(D_MODEL / 64, LL / 64, BB), blk256, 0, stream>>>(
      P_bf, (size_t)LL * LL, encT, (size_t)D_MODEL * LL,
      h2, (size_t)LL * D_MODEL, LL, D_MODEL, LL);

  for (int i = N_LAYER / 2; i < N_LAYER; ++i) mamba(h2, i);

  rmsnorm_kernel<<<MTOK * 64 / 256, blk256, 0, stream>>>(h2, normf_w, hn, hn_bf, MTOK, D_MODEL);
  gemm_f32<0><<<dim3((N_MELS + BNt - 1) / BNt, MTOK / BMt), blk256, 0, stream>>>(
      hn, D_MODEL, w_out, N_MELS, nullptr, (float*)d_out, N_MELS, MTOK, N_MELS, D_MODEL);
}